// Round 3
// baseline (4762.218 us; speedup 1.0000x reference)
//
#include <hip/hip_runtime.h>
#include <hip/hip_bf16.h>
#include <stdint.h>

typedef __bf16 bf16_t;
typedef __bf16 bf16x8 __attribute__((ext_vector_type(8)));
typedef __bf16 bf16x4 __attribute__((ext_vector_type(4)));
typedef float  f32x4  __attribute__((ext_vector_type(4)));

#define SEQ   512
#define BATCH 32
#define HID   1024
#define FFD   4096
#define NROW  (SEQ*BATCH)          /* 16384 rows, layout [s][b][feat] */
#define NTOT  ((long)NROW*HID)     /* 16,777,216 */

typedef __attribute__((address_space(3))) uint32_t lds_u32;
typedef __attribute__((address_space(1))) const uint32_t glb_u32;

__device__ __forceinline__ void gload_lds16(const void* g, void* l) {
  glb_u32* gp = reinterpret_cast<glb_u32*>(reinterpret_cast<uintptr_t>(g));
  lds_u32* lp = reinterpret_cast<lds_u32*>(reinterpret_cast<uintptr_t>(l));
  __builtin_amdgcn_global_load_lds(gp, lp, 16, 0, 0);
}

#define BAR() asm volatile("s_barrier" ::: "memory")

// ---------------- embedding: h = emb[x]*32 + pos[s]; also bf16 copy --------
__global__ __launch_bounds__(256) void embed_k(const int* __restrict__ x,
    const float* __restrict__ emb, const float* __restrict__ pos,
    float* __restrict__ h, bf16_t* __restrict__ hb)
{
  const long row = blockIdx.x;           // row = s*32 + b
  const int  s   = (int)(row >> 5);
  const long idx = x[row];
  const int  t   = threadIdx.x;
  float4 e  = ((const float4*)(emb + idx*HID))[t];
  float4 pv = ((const float4*)(pos + (long)s*HID))[t];
  float4 o  = {e.x*32.f+pv.x, e.y*32.f+pv.y, e.z*32.f+pv.z, e.w*32.f+pv.w};
  ((float4*)(h + row*HID))[t] = o;
  bf16x4 ob = {(bf16_t)o.x, (bf16_t)o.y, (bf16_t)o.z, (bf16_t)o.w};
  *(bf16x4*)(hb + row*HID + (long)t*4) = ob;
}

// ------------- weight convert + transpose: wT[n][k] = bf16(w[k][n]) --------
__global__ __launch_bounds__(256) void wcvt(const float* __restrict__ w,
    bf16_t* __restrict__ wT, int K, int N)
{
  __shared__ float tile[32][33];
  const int tx = threadIdx.x & 31, ty = threadIdx.x >> 5;   // ty 0..7
  const int ntx = N >> 5;
  const int n0 = (blockIdx.x % ntx) << 5;
  const int k0 = (blockIdx.x / ntx) << 5;
#pragma unroll
  for (int i = 0; i < 4; ++i)
    tile[ty + i*8][tx] = w[(long)(k0 + ty + i*8)*N + n0 + tx];
  __syncthreads();
#pragma unroll
  for (int i = 0; i < 4; ++i)
    wT[(long)(n0 + ty + i*8)*K + k0 + tx] = (bf16_t)tile[tx][ty + i*8];
}

// ====== bf16 MFMA GEMM, 256x256 tile, BK=32, 8 waves, derived-waits ========
// C[M,N] = A[M,K] * Bt[N,K]^T (+bias)
// MODE 0: outB=bf16(acc+bias)  MODE 1: outB=bf16(relu(acc+bias))  MODE 2: outF=acc+bias+res
//
// Pipeline: LDS triple-buffered (tile t in buf t%3); stages go 2 tiles ahead
// (A halves in phases 0/1, B halves in phases 2/3) so every staged half has
// >=4 phases of lead. Register fragments are read ONE phase before their
// consuming MFMA cluster (aLo/aHi/b0/b1 each have a dead phase before refill,
// so no double buffering). Only 3 barriers per tile, each preceded by a
// counted vmcnt that publishes exactly the half-tile the next phase reads:
//   vmcnt(5) -> A(t+1)h0 ready for aLo' reads
//   vmcnt(4) -> A(t+1)h1 + B(t+1)h0 ready for b0' reads
//   vmcnt(4) -> B(t+1)h1 ready for next ph0's b1'/aHi' reads
// Tail: stages/reads are unconditional with wrapped indices so counts stay
// constant (junk lands in a buffer that is never consumed).
template<int MODE>
__global__ __launch_bounds__(512, 2)
void gemm256(const bf16_t* __restrict__ A, const bf16_t* __restrict__ Bt,
             const float* bias, const float* res,
             float* __restrict__ outF, bf16_t* __restrict__ outB,
             int M, int N, int K)
{
  __shared__ bf16_t As[3][256*32];
  __shared__ bf16_t Bs[3][256*32];
  const int tid = threadIdx.x;
  const int w = tid >> 6, l = tid & 63;
  const int wm = w >> 2, wn = w & 3;

  // bijective XCD swizzle (m204)
  const int nbn = N >> 8;
  const int nwg = gridDim.x;
  const int q8 = nwg >> 3, r8 = nwg & 7;
  const int xcd = blockIdx.x & 7, bidx = blockIdx.x >> 3;
  const int wg = (xcd < r8 ? xcd*(q8+1) : r8*(q8+1) + (xcd-r8)*q8) + bidx;
  const long bm = wg / nbn, bn = wg % nbn;
  const long rA0 = bm << 8, rB0 = bn << 8;

  // staging: 512 threads cover one 128-row half (row=tid>>2, 16B slot=tid&3);
  // LDS dest is linear (base + lane*16); global source column pre-swizzled by
  // the involution slot ^= (r&3) ^ ((r>>2)&1)
  const int srow   = tid >> 2;                 // 0..127 within half
  const int schunk = (((tid & 3) ^ ((tid >> 2) & 3) ^ ((tid >> 4) & 1)) << 3);
  const int sldso  = w << 10;                  // wave byte base within half

  const int fr = l & 15;
  const int g4 = (l >> 4) & 3;                 // k-chunk selector

  f32x4 acc[8][4];
#pragma unroll
  for (int m = 0; m < 8; ++m)
#pragma unroll
    for (int n = 0; n < 4; ++n) acc[m][n] = (f32x4){0.f,0.f,0.f,0.f};

#define STG(G, r0, buf, h, kt) \
  gload_lds16((G) + ((r0) + (h)*128 + srow)*(long)K + (long)(kt)*32 + schunk, \
              (char*)(buf) + (h)*8192 + sldso)

  // swizzled fragment read: row r (0..255), 16B slot g4 ^ (r&3) ^ ((r>>2)&1)
#define FR(buf, r) \
  (*(const bf16x8*)((const char*)(buf) + (r)*64 + ((g4 ^ ((r)&3) ^ (((r)>>2)&1)) << 4)))

  bf16_t *Ac = &As[0][0], *An = &As[1][0], *An2 = &As[2][0];
  bf16_t *Bc = &Bs[0][0], *Bn = &Bs[1][0], *Bn2 = &Bs[2][0];

  const int nk = K >> 5;

  bf16x8 aA[4], aB[4], bA[2], bB[2];

  // prologue: tile0 (4 halves) + tile1 (4 halves) in flight
  STG(A,  rA0, Ac, 0, 0); STG(A,  rA0, Ac, 1, 0);
  STG(Bt, rB0, Bc, 0, 0); STG(Bt, rB0, Bc, 1, 0);
  STG(A,  rA0, An, 0, 1); STG(A,  rA0, An, 1, 1);
  STG(Bt, rB0, Bn, 0, 1); STG(Bt, rB0, Bn, 1, 1);
  asm volatile("s_waitcnt vmcnt(4)" ::: "memory");   // tile0 resident
  BAR();
#pragma unroll
  for (int m = 0; m < 4; ++m) aA[m] = FR(Ac, m*32 + wm*16 + fr);
#pragma unroll
  for (int n = 0; n < 2; ++n) bA[n] = FR(Bc, n*64 + wn*16 + fr);

  for (int t = 0; t < nk; ++t) {
    int kt = t + 2; if (kt >= nk) kt -= nk;          // wrapped stage index

    // ---- phase 0: MFMA Q00(aA,bA); read b1,aHi; stage A(t+2)h0
    bB[0] = FR(Bc, 128 + wn*16 + fr);
    bB[1] = FR(Bc, 192 + wn*16 + fr);
#pragma unroll
    for (int m = 0; m < 4; ++m) aB[m] = FR(Ac, 128 + m*32 + wm*16 + fr);
    STG(A, rA0, An2, 0, kt);
    __builtin_amdgcn_s_setprio(1);
#pragma unroll
    for (int m = 0; m < 4; ++m)
#pragma unroll
      for (int n = 0; n < 2; ++n)
        acc[m][n] = __builtin_amdgcn_mfma_f32_16x16x32_bf16(aA[m], bA[n], acc[m][n], 0, 0, 0);
    __builtin_amdgcn_s_setprio(0);

    // ---- phase 1: MFMA Q01(aA,bB); stage A(t+2)h1
    STG(A, rA0, An2, 1, kt);
    __builtin_amdgcn_s_setprio(1);
#pragma unroll
    for (int m = 0; m < 4; ++m)
#pragma unroll
      for (int n = 0; n < 2; ++n)
        acc[m][2+n] = __builtin_amdgcn_mfma_f32_16x16x32_bf16(aA[m], bB[n], acc[m][2+n], 0, 0, 0);
    __builtin_amdgcn_s_setprio(0);
    asm volatile("s_waitcnt vmcnt(5)" ::: "memory"); // A(t+1)h0 landed
    BAR();

    // ---- phase 2: MFMA Q10(aB,bA); read aLo(t+1); stage B(t+2)h0
#pragma unroll
    for (int m = 0; m < 4; ++m) aA[m] = FR(An, m*32 + wm*16 + fr);
    STG(Bt, rB0, Bn2, 0, kt);
    __builtin_amdgcn_s_setprio(1);
#pragma unroll
    for (int m = 0; m < 4; ++m)
#pragma unroll
      for (int n = 0; n < 2; ++n)
        acc[4+m][n] = __builtin_amdgcn_mfma_f32_16x16x32_bf16(aB[m], bA[n], acc[4+m][n], 0, 0, 0);
    __builtin_amdgcn_s_setprio(0);
    asm volatile("s_waitcnt vmcnt(4)" ::: "memory"); // A(t+1)h1, B(t+1)h0 landed
    BAR();

    // ---- phase 3: MFMA Q11(aB,bB); read b0(t+1); stage B(t+2)h1
    bA[0] = FR(Bn, wn*16 + fr);
    bA[1] = FR(Bn, 64 + wn*16 + fr);
    STG(Bt, rB0, Bn2, 1, kt);
    __builtin_amdgcn_s_setprio(1);
#pragma unroll
    for (int m = 0; m < 4; ++m)
#pragma unroll
      for (int n = 0; n < 2; ++n)
        acc[4+m][2+n] = __builtin_amdgcn_mfma_f32_16x16x32_bf16(aB[m], bB[n], acc[4+m][2+n], 0, 0, 0);
    __builtin_amdgcn_s_setprio(0);
    asm volatile("s_waitcnt vmcnt(4)" ::: "memory"); // B(t+1)h1 landed
    BAR();

    // rotate triple buffers
    bf16_t* ta = Ac; Ac = An; An = An2; An2 = ta;
    bf16_t* tb = Bc; Bc = Bn; Bn = Bn2; Bn2 = tb;
  }
#undef STG
#undef FR

  // epilogue — launder pointers so vmem loads can't hoist into the loop
  uintptr_t bp = (uintptr_t)bias;  asm volatile("" : "+v"(bp));
  uintptr_t rp = (uintptr_t)res;   asm volatile("" : "+v"(rp));
  const float* biasq = (const float*)bp;
  const float* resq  = (const float*)rp;
  const int er = (l >> 4) << 2;
#pragma unroll
  for (int n = 0; n < 4; ++n) {
    const long col = rB0 + (n >> 1)*128 + (n & 1)*64 + wn*16 + fr;
    const float bv = biasq[col];
#pragma unroll
    for (int m = 0; m < 8; ++m) {
      const long row0 = rA0 + (m >> 2)*128 + (m & 3)*32 + wm*16 + er;
#pragma unroll
      for (int j = 0; j < 4; ++j) {
        const long off = (row0 + j)*(long)N + col;
        const float v = acc[m][n][j] + bv;
        if (MODE == 0)      outB[off] = (bf16_t)v;
        else if (MODE == 1) outB[off] = (bf16_t)fmaxf(v, 0.f);
        else                outF[off] = v + resq[off];
      }
    }
  }
}

// ---------------- attention: one block per (b, head) -----------------------
__global__ __launch_bounds__(256) void attn_k(
    const bf16_t* __restrict__ qb, const bf16_t* __restrict__ kb,
    const bf16_t* __restrict__ vb, bf16_t* __restrict__ ob)
{
  __shared__ __align__(16) char smem[64*128*2*2 + 64*64*4 + 64*4];
  bf16_t* Qc = (bf16_t*)smem;
  bf16_t* Kc = (bf16_t*)(smem + 16384);
  bf16_t* Vc = (bf16_t*)smem;                  // aliases Qc (phase-disjoint)
  float*  E    = (float*)(smem + 32768);
  float*  Rinv = (float*)(smem + 49152);

  const int tid  = threadIdx.x;
  const int head = blockIdx.x & 7, b = blockIdx.x >> 3;
  const long rbase = (long)head*32 + b;

  const int ti = tid >> 2, g = tid & 3;
  const int lr  = tid >> 2;
  const int lp0 = (tid & 3) * 4;

  float eacc[16];
#pragma unroll
  for (int j = 0; j < 16; ++j) eacc[j] = 0.f;

  for (int kc = 0; kc < HID; kc += 128) {
    __syncthreads();
    const bf16_t* qrow = qb + (lr*256 + rbase)*HID + kc;
    const bf16_t* krow = kb + (lr*256 + rbase)*HID + kc;
#pragma unroll
    for (int i = 0; i < 4; ++i) {
      const int p = lp0 + i;
      const int src = (p ^ (lr & 7)) * 8;
      *(uint4*)&Qc[lr*128 + p*8] = *(const uint4*)&qrow[src];
      *(uint4*)&Kc[lr*128 + p*8] = *(const uint4*)&krow[src];
    }
    __syncthreads();
    for (int e8 = 0; e8 < 16; ++e8) {
      const int qp = e8 ^ (ti & 7);
      bf16x8 qv = *(bf16x8*)&Qc[ti*128 + qp*8];
      float qf[8];
#pragma unroll
      for (int u = 0; u < 8; ++u) qf[u] = (float)qv[u];
#pragma unroll
      for (int j = 0; j < 16; ++j) {
        const int s  = j*4 + g;
        const int kp = e8 ^ (s & 7);
        bf16x8 kv = *(bf16x8*)&Kc[s*128 + kp*8];
        float a = eacc[j];
#pragma unroll
        for (int u = 0; u < 8; ++u) a += qf[u] * (float)kv[u];
        eacc[j] = a;
      }
    }
  }
  const float scale = 0.0883883476483184f;     // 1/sqrt(128)
  float mx = -1e30f;
#pragma unroll
  for (int j = 0; j < 16; ++j) { eacc[j] *= scale; mx = fmaxf(mx, eacc[j]); }
  mx = fmaxf(mx, __shfl_xor(mx, 1));
  mx = fmaxf(mx, __shfl_xor(mx, 2));
  float sum = 0.f;
#pragma unroll
  for (int j = 0; j < 16; ++j) {
    const float pj = __expf(eacc[j] - mx);
    E[(j*4 + g)*64 + ti] = pj;
    sum += pj;
  }
  sum += __shfl_xor(sum, 1);
  sum += __shfl_xor(sum, 2);
  if (g == 0) Rinv[ti] = 1.f / sum;
  __syncthreads();

  const int lane = tid & 63, wq_ = tid >> 6;
  const float rv = Rinv[lane];
  const long orow = (long)lane*256 + b*8 + head;
  for (int fc = 0; fc < HID; fc += 128) {
    __syncthreads();
    const bf16_t* vrow = vb + (lr*256 + rbase)*HID + fc;
#pragma unroll
    for (int i = 0; i < 4; ++i) {
      const int p = lp0 + i;
      *(uint4*)&Vc[lr*128 + p*8] = *(const uint4*)&vrow[p*8];
    }
    __syncthreads();
    float vacc[32];
#pragma unroll
    for (int u = 0; u < 32; ++u) vacc[u] = 0.f;
    for (int s = 0; s < 64; ++s) {
      const float pp = E[s*64 + lane];
#pragma unroll
      for (int u = 0; u < 4; ++u) {
        bf16x8 vv = *(bf16x8*)&Vc[s*128 + wq_*32 + u*8];
#pragma unroll
        for (int t8 = 0; t8 < 8; ++t8) vacc[u*8 + t8] += pp * (float)vv[t8];
      }
    }
#pragma unroll
    for (int u = 0; u < 4; ++u) {
      bf16x8 ov;
#pragma unroll
      for (int t8 = 0; t8 < 8; ++t8) ov[t8] = (bf16_t)(vacc[u*8 + t8] * rv);
      *(bf16x8*)&ob[orow*HID + fc + wq_*32 + u*8] = ov;
    }
  }
}

// ---------------- global layer-norm: 2-stage reduce + normalize ------------
__global__ __launch_bounds__(256) void reduce1(const float* __restrict__ t,
                                               float* __restrict__ part, long n4)
{
  float s = 0.f, s2 = 0.f;
  for (long i = (long)blockIdx.x*blockDim.x + threadIdx.x; i < n4;
       i += (long)gridDim.x*blockDim.x) {
    float4 v = ((const float4*)t)[i];
    s  += v.x + v.y + v.z + v.w;
    s2 += v.x*v.x + v.y*v.y + v.z*v.z + v.w*v.w;
  }
  __shared__ float sh[256], sh2[256];
  const int tid = threadIdx.x;
  sh[tid] = s; sh2[tid] = s2; __syncthreads();
  for (int o = 128; o > 0; o >>= 1) {
    if (tid < o) { sh[tid] += sh[tid+o]; sh2[tid] += sh2[tid+o]; }
    __syncthreads();
  }
  if (tid == 0) { part[blockIdx.x] = sh[0]; part[2048 + blockIdx.x] = sh2[0]; }
}

__global__ __launch_bounds__(256) void reduce2(const float* __restrict__ part,
                                               float* __restrict__ stats)
{
  __shared__ double sh[256], sh2[256];
  const int tid = threadIdx.x;
  double s = 0.0, s2 = 0.0;
  for (int i = tid; i < 2048; i += 256) { s += part[i]; s2 += part[2048 + i]; }
  sh[tid] = s; sh2[tid] = s2; __syncthreads();
  for (int o = 128; o > 0; o >>= 1) {
    if (tid < o) { sh[tid] += sh[tid+o]; sh2[tid] += sh2[tid+o]; }
    __syncthreads();
  }
  if (tid == 0) {
    const double n = (double)NTOT;
    const double mean = sh[0] / n;
    const double var  = sh2[0] / n - mean*mean;
    stats[0] = (float)mean;
    stats[1] = (float)(1.0 / sqrt(var + 1e-5));
  }
}

__global__ __launch_bounds__(256) void ln_norm(const float* __restrict__ t,
    const float* __restrict__ stats, float* __restrict__ outF,
    bf16_t* __restrict__ outB, long n4)
{
  const float mean = stats[0], rstd = stats[1];
  for (long i = (long)blockIdx.x*blockDim.x + threadIdx.x; i < n4;
       i += (long)gridDim.x*blockDim.x) {
    float4 v = ((const float4*)t)[i];
    float4 o = {(v.x-mean)*rstd, (v.y-mean)*rstd, (v.z-mean)*rstd, (v.w-mean)*rstd};
    ((float4*)outF)[i] = o;
    bf16x4 ob = {(bf16_t)o.x, (bf16_t)o.y, (bf16_t)o.z, (bf16_t)o.w};
    ((bf16x4*)outB)[i] = ob;
  }
}

// ---------------------------------------------------------------------------
extern "C" void kernel_launch(void* const* d_in, const int* in_sizes, int n_in,
                              void* d_out, int out_size, void* d_ws, size_t ws_size,
                              hipStream_t stream)
{
  const int*   x    = (const int*)  d_in[0];
  const float* emb  = (const float*)d_in[1];
  const float* pos  = (const float*)d_in[2];
  const float* wq_a = (const float*)d_in[3];
  const float* bq_a = (const float*)d_in[4];
  const float* wk_a = (const float*)d_in[5];
  const float* bk_a = (const float*)d_in[6];
  const float* wv_a = (const float*)d_in[7];
  const float* bv_a = (const float*)d_in[8];
  const float* wo_a = (const float*)d_in[9];
  const float* bo_a = (const float*)d_in[10];
  const float* w1_a = (const float*)d_in[11];
  const float* b1_a = (const float*)d_in[12];
  const float* w2_a = (const float*)d_in[13];
  const float* b2_a = (const float*)d_in[14];

  char* p = (char*)d_ws;
  auto take = [&](size_t n) { char* r = p; p += (n + 255) & ~(size_t)255; return r; };
  float*  h    = (float*) take(NTOT*4);
  bf16_t* hb   = (bf16_t*)take(NTOT*2);
  bf16_t* U    = (bf16_t*)take((size_t)NROW*FFD*2);
  bf16_t* qb   = U;
  bf16_t* kb   = U + NTOT;
  bf16_t* vbuf = U + 2*NTOT;
  bf16_t* attb = U + 3*NTOT;
  bf16_t* ff1  = U;
  bf16_t* wT   = (bf16_t*)take((size_t)FFD*HID*2);
  float*  part = (float*) take(4096*4);
  float*  stats= (float*) take(256);

  const long n4 = NTOT / 4;
  const int gH  = (NROW/256)*(HID/256);                 // 256 blocks
  const int gF  = (NROW/256)*(FFD/256);                 // 1024 blocks

  embed_k<<<NROW, 256, 0, stream>>>(x, emb, pos, h, hb);

  for (int i = 0; i < 6; ++i) {
    const float* Wq = wq_a + (size_t)i*HID*HID;  const float* Bq = bq_a + (size_t)i*HID;
    const float* Wk = wk_a + (size_t)i*HID*HID;  const float* Bk = bk_a + (size_t)i*HID;
    const float* Wv = wv_a + (size_t)i*HID*HID;  const float* Bv = bv_a + (size_t)i*HID;
    const float* Wo = wo_a + (size_t)i*HID*HID;  const float* Bo = bo_a + (size_t)i*HID;
    const float* W1 = w1_a + (size_t)i*HID*FFD;  const float* B1 = b1_a + (size_t)i*FFD;
    const float* W2 = w2_a + (size_t)i*FFD*HID;  const float* B2 = b2_a + (size_t)i*HID;

    wcvt<<<(HID/32)*(HID/32), 256, 0, stream>>>(Wq, wT, HID, HID);
    gemm256<0><<<gH, 512, 0, stream>>>(hb, wT, Bq, nullptr, nullptr, qb, NROW, HID, HID);
    wcvt<<<(HID/32)*(HID/32), 256, 0, stream>>>(Wk, wT, HID, HID);
    gemm256<0><<<gH, 512, 0, stream>>>(hb, wT, Bk, nullptr, nullptr, kb, NROW, HID, HID);
    wcvt<<<(HID/32)*(HID/32), 256, 0, stream>>>(Wv, wT, HID, HID);
    gemm256<0><<<gH, 512, 0, stream>>>(hb, wT, Bv, nullptr, nullptr, vbuf, NROW, HID, HID);

    attn_k<<<256, 256, 0, stream>>>(qb, kb, vbuf, attb);

    wcvt<<<(HID/32)*(HID/32), 256, 0, stream>>>(Wo, wT, HID, HID);
    gemm256<2><<<gH, 512, 0, stream>>>(attb, wT, Bo, h, h, nullptr, NROW, HID, HID);

    reduce1<<<2048, 256, 0, stream>>>(h, part, n4);
    reduce2<<<1, 256, 0, stream>>>(part, stats);
    ln_norm<<<2048, 256, 0, stream>>>(h, stats, h, hb, n4);

    wcvt<<<(FFD/32)*(HID/32), 256, 0, stream>>>(W1, wT, HID, FFD);
    gemm256<1><<<gF, 512, 0, stream>>>(hb, wT, B1, nullptr, nullptr, ff1, NROW, FFD, HID);
    wcvt<<<(HID/32)*(FFD/32), 256, 0, stream>>>(W2, wT, FFD, HID);
    gemm256<2><<<gH, 512, 0, stream>>>(ff1, wT, B2, h, h, nullptr, NROW, HID, FFD);

    reduce1<<<2048, 256, 0, stream>>>(h, part, n4);
    reduce2<<<1, 256, 0, stream>>>(part, stats);
    ln_norm<<<2048, 256, 0, stream>>>(h, stats, (i == 5) ? (float*)d_out : h, hb, n4);
  }
}

// Round 4
// 4656.976 us; speedup vs baseline: 1.0226x; 1.0226x over previous
//
#include <hip/hip_runtime.h>
#include <hip/hip_bf16.h>
#include <stdint.h>

typedef __bf16 bf16_t;
typedef __bf16 bf16x8 __attribute__((ext_vector_type(8)));
typedef __bf16 bf16x4 __attribute__((ext_vector_type(4)));
typedef float  f32x4  __attribute__((ext_vector_type(4)));

#define SEQ   512
#define BATCH 32
#define HID   1024
#define FFD   4096
#define NROW  (SEQ*BATCH)          /* 16384 rows, layout [s][b][feat] */
#define NTOT  ((long)NROW*HID)     /* 16,777,216 */

typedef __attribute__((address_space(3))) uint32_t lds_u32;
typedef __attribute__((address_space(1))) const uint32_t glb_u32;

__device__ __forceinline__ void gload_lds16(const void* g, void* l) {
  glb_u32* gp = reinterpret_cast<glb_u32*>(reinterpret_cast<uintptr_t>(g));
  lds_u32* lp = reinterpret_cast<lds_u32*>(reinterpret_cast<uintptr_t>(l));
  __builtin_amdgcn_global_load_lds(gp, lp, 16, 0, 0);
}

#define BAR() asm volatile("s_barrier" ::: "memory")

// ---------------- embedding: h = emb[x]*32 + pos[s]; also bf16 copy --------
__global__ __launch_bounds__(256) void embed_k(const int* __restrict__ x,
    const float* __restrict__ emb, const float* __restrict__ pos,
    float* __restrict__ h, bf16_t* __restrict__ hb)
{
  const long row = blockIdx.x;           // row = s*32 + b
  const int  s   = (int)(row >> 5);
  const long idx = x[row];
  const int  t   = threadIdx.x;
  float4 e  = ((const float4*)(emb + idx*HID))[t];
  float4 pv = ((const float4*)(pos + (long)s*HID))[t];
  float4 o  = {e.x*32.f+pv.x, e.y*32.f+pv.y, e.z*32.f+pv.z, e.w*32.f+pv.w};
  ((float4*)(h + row*HID))[t] = o;
  bf16x4 ob = {(bf16_t)o.x, (bf16_t)o.y, (bf16_t)o.z, (bf16_t)o.w};
  *(bf16x4*)(hb + row*HID + (long)t*4) = ob;
}

// ------------- weight convert + transpose: wT[n][k] = bf16(w[k][n]) --------
__global__ __launch_bounds__(256) void wcvt(const float* __restrict__ w,
    bf16_t* __restrict__ wT, int K, int N)
{
  __shared__ float tile[32][33];
  const int tx = threadIdx.x & 31, ty = threadIdx.x >> 5;   // ty 0..7
  const int ntx = N >> 5;
  const int n0 = (blockIdx.x % ntx) << 5;
  const int k0 = (blockIdx.x / ntx) << 5;
#pragma unroll
  for (int i = 0; i < 4; ++i)
    tile[ty + i*8][tx] = w[(long)(k0 + ty + i*8)*N + n0 + tx];
  __syncthreads();
#pragma unroll
  for (int i = 0; i < 4; ++i)
    wT[(long)(n0 + ty + i*8)*K + k0 + tx] = (bf16_t)tile[tx][ty + i*8];
}

// ====== bf16 MFMA GEMM, 256x256 tile, BK=64, 8 waves, 2 barriers/tile ======
// C[M,N] = A[M,K] * Bt[N,K]^T (+bias)
// MODE 0: outB=bf16(acc+bias)  MODE 1: outB=bf16(relu(acc+bias))  MODE 2: outF=acc+bias+res
//
// Per K-tile: read ALL 24 fragments, then one unbroken 64-MFMA cluster
// (compiler's FIFO lgkm waits start MFMA after the first frags land; the
// rest of the reads service under the MFMA; co-SIMD waves drift freely).
// Then: BAR (cur fully read) -> STAGE(t+2 -> cur, 8 loads) -> vmcnt(8)
// (retires exactly tile t+1's 8 loads; never drains) -> BAR (t+1 visible).
// Tail: stages use wrapped indices so vmcnt counts stay constant.
template<int MODE>
__global__ __launch_bounds__(512, 2)
void gemm256(const bf16_t* __restrict__ A, const bf16_t* __restrict__ Bt,
             const float* bias, const float* res,
             float* __restrict__ outF, bf16_t* __restrict__ outB,
             int M, int N, int K)
{
  __shared__ bf16_t As[2][256*64];
  __shared__ bf16_t Bs[2][256*64];
  const int tid = threadIdx.x;
  const int w = tid >> 6, l = tid & 63;
  const int wm = w >> 2, wn = w & 3;

  // bijective XCD swizzle (m204)
  const int nbn = N >> 8;
  const int nwg = gridDim.x;
  const int q8 = nwg >> 3, r8 = nwg & 7;
  const int xcd = blockIdx.x & 7, bidx = blockIdx.x >> 3;
  const int wg = (xcd < r8 ? xcd*(q8+1) : r8*(q8+1) + (xcd-r8)*q8) + bidx;
  const long bm = wg / nbn, bn = wg % nbn;
  const long rA0 = bm << 8, rB0 = bn << 8;

  // staging geometry: 512 threads cover one 128-row half in 2 loads/thread
  const int srow  = tid >> 3;                       // 0..63
  const int scol  = (((tid & 7) ^ (srow & 7)) << 3);// swizzled src col (elems)
  const int wrow  = w << 3;                         // wave row base (0..56)

  const int fr  = l & 15;
  const int fk2 = (l >> 4) << 4;                    // frag k byte offset {0,16,32,48}

  f32x4 acc[8][4];
#pragma unroll
  for (int m = 0; m < 8; ++m)
#pragma unroll
    for (int n = 0; n < 4; ++n) acc[m][n] = (f32x4){0.f,0.f,0.f,0.f};

#define STAGE_A(b, kt) do { \
    const long kb_ = (long)(kt)*64 + scol; \
    gload_lds16(A + (rA0 + srow)*(long)K + kb_,        (void*)&As[b][wrow*64]); \
    gload_lds16(A + (rA0 + 64 + srow)*(long)K + kb_,   (void*)&As[b][(64 + wrow)*64]); \
    gload_lds16(A + (rA0 + 128 + srow)*(long)K + kb_,  (void*)&As[b][(128 + wrow)*64]); \
    gload_lds16(A + (rA0 + 192 + srow)*(long)K + kb_,  (void*)&As[b][(192 + wrow)*64]); \
  } while (0)
#define STAGE_B(b, kt) do { \
    const long kb_ = (long)(kt)*64 + scol; \
    gload_lds16(Bt + (rB0 + srow)*(long)K + kb_,       (void*)&Bs[b][wrow*64]); \
    gload_lds16(Bt + (rB0 + 64 + srow)*(long)K + kb_,  (void*)&Bs[b][(64 + wrow)*64]); \
    gload_lds16(Bt + (rB0 + 128 + srow)*(long)K + kb_, (void*)&Bs[b][(128 + wrow)*64]); \
    gload_lds16(Bt + (rB0 + 192 + srow)*(long)K + kb_, (void*)&Bs[b][(192 + wrow)*64]); \
  } while (0)
#define FRAG(base, r, kk) \
    (*(const bf16x8*)((const char*)(base) + (r)*128 + (((kk)*64 + fk2) ^ (((r) & 7) << 4))))

  const int nk = K >> 6;

  // prologue: tile0 -> buf0, drain; tile1 -> buf1 left in flight (8)
  STAGE_A(0, 0); STAGE_B(0, 0);
  asm volatile("s_waitcnt vmcnt(0)" ::: "memory");
  BAR();
  STAGE_A(1, 1); STAGE_B(1, 1);

  int cur = 0;
  for (int t = 0; t < nk; ++t) {
    const bf16_t* Ac = As[cur];
    const bf16_t* Bc = Bs[cur];
    int kt = t + 2; if (kt >= nk) kt -= nk;          // wrapped stage index

    bf16x8 af[8][2], bf[4][2];
#pragma unroll
    for (int m = 0; m < 8; ++m) {
      const int r = (m >> 2)*128 + (m & 3)*32 + wm*16 + fr;
#pragma unroll
      for (int kk = 0; kk < 2; ++kk) af[m][kk] = FRAG(Ac, r, kk);
    }
#pragma unroll
    for (int n = 0; n < 4; ++n) {
      const int r = (n >> 1)*128 + (n & 1)*64 + wn*16 + fr;
#pragma unroll
      for (int kk = 0; kk < 2; ++kk) bf[n][kk] = FRAG(Bc, r, kk);
    }

    // one unbroken 64-MFMA cluster
#pragma unroll
    for (int m = 0; m < 8; ++m)
#pragma unroll
      for (int n = 0; n < 4; ++n)
#pragma unroll
        for (int kk = 0; kk < 2; ++kk)
          acc[m][n] = __builtin_amdgcn_mfma_f32_16x16x32_bf16(af[m][kk], bf[n][kk], acc[m][n], 0, 0, 0);

    BAR();                                           // everyone done reading cur
    if (MODE >= 0) { STAGE_A(cur, kt); STAGE_B(cur, kt); }  // t+2 -> cur
    asm volatile("s_waitcnt vmcnt(8)" ::: "memory"); // retire tile t+1's loads
    BAR();                                           // t+1 visible to all
    cur ^= 1;
  }
#undef STAGE_A
#undef STAGE_B
#undef FRAG

  // epilogue — launder pointers so vmem loads can't hoist into the loop
  uintptr_t bp = (uintptr_t)bias;  asm volatile("" : "+v"(bp));
  uintptr_t rp = (uintptr_t)res;   asm volatile("" : "+v"(rp));
  const float* biasq = (const float*)bp;
  const float* resq  = (const float*)rp;
  const int er = (l >> 4) << 2;
#pragma unroll
  for (int n = 0; n < 4; ++n) {
    const long col = rB0 + (n >> 1)*128 + (n & 1)*64 + wn*16 + fr;
    const float bv = biasq[col];
#pragma unroll
    for (int m = 0; m < 8; ++m) {
      const long row0 = rA0 + (m >> 2)*128 + (m & 3)*32 + wm*16 + er;
#pragma unroll
      for (int j = 0; j < 4; ++j) {
        const long off = (row0 + j)*(long)N + col;
        const float v = acc[m][n][j] + bv;
        if (MODE == 0)      outB[off] = (bf16_t)v;
        else if (MODE == 1) outB[off] = (bf16_t)fmaxf(v, 0.f);
        else                outF[off] = v + resq[off];
      }
    }
  }
}

// ---------------- attention: one block per (b, head) -----------------------
__global__ __launch_bounds__(256) void attn_k(
    const bf16_t* __restrict__ qb, const bf16_t* __restrict__ kb,
    const bf16_t* __restrict__ vb, bf16_t* __restrict__ ob)
{
  __shared__ __align__(16) char smem[64*128*2*2 + 64*64*4 + 64*4];
  bf16_t* Qc = (bf16_t*)smem;
  bf16_t* Kc = (bf16_t*)(smem + 16384);
  bf16_t* Vc = (bf16_t*)smem;                  // aliases Qc (phase-disjoint)
  float*  E    = (float*)(smem + 32768);
  float*  Rinv = (float*)(smem + 49152);

  const int tid  = threadIdx.x;
  const int head = blockIdx.x & 7, b = blockIdx.x >> 3;
  const long rbase = (long)head*32 + b;

  const int ti = tid >> 2, g = tid & 3;
  const int lr  = tid >> 2;
  const int lp0 = (tid & 3) * 4;

  float eacc[16];
#pragma unroll
  for (int j = 0; j < 16; ++j) eacc[j] = 0.f;

  for (int kc = 0; kc < HID; kc += 128) {
    __syncthreads();
    const bf16_t* qrow = qb + (lr*256 + rbase)*HID + kc;
    const bf16_t* krow = kb + (lr*256 + rbase)*HID + kc;
#pragma unroll
    for (int i = 0; i < 4; ++i) {
      const int p = lp0 + i;
      const int src = (p ^ (lr & 7)) * 8;
      *(uint4*)&Qc[lr*128 + p*8] = *(const uint4*)&qrow[src];
      *(uint4*)&Kc[lr*128 + p*8] = *(const uint4*)&krow[src];
    }
    __syncthreads();
    for (int e8 = 0; e8 < 16; ++e8) {
      const int qp = e8 ^ (ti & 7);
      bf16x8 qv = *(bf16x8*)&Qc[ti*128 + qp*8];
      float qf[8];
#pragma unroll
      for (int u = 0; u < 8; ++u) qf[u] = (float)qv[u];
#pragma unroll
      for (int j = 0; j < 16; ++j) {
        const int s  = j*4 + g;
        const int kp = e8 ^ (s & 7);
        bf16x8 kv = *(bf16x8*)&Kc[s*128 + kp*8];
        float a = eacc[j];
#pragma unroll
        for (int u = 0; u < 8; ++u) a += qf[u] * (float)kv[u];
        eacc[j] = a;
      }
    }
  }
  const float scale = 0.0883883476483184f;     // 1/sqrt(128)
  float mx = -1e30f;
#pragma unroll
  for (int j = 0; j < 16; ++j) { eacc[j] *= scale; mx = fmaxf(mx, eacc[j]); }
  mx = fmaxf(mx, __shfl_xor(mx, 1));
  mx = fmaxf(mx, __shfl_xor(mx, 2));
  float sum = 0.f;
#pragma unroll
  for (int j = 0; j < 16; ++j) {
    const float pj = __expf(eacc[j] - mx);
    E[(j*4 + g)*64 + ti] = pj;
    sum += pj;
  }
  sum += __shfl_xor(sum, 1);
  sum += __shfl_xor(sum, 2);
  if (g == 0) Rinv[ti] = 1.f / sum;
  __syncthreads();

  const int lane = tid & 63, wq_ = tid >> 6;
  const float rv = Rinv[lane];
  const long orow = (long)lane*256 + b*8 + head;
  for (int fc = 0; fc < HID; fc += 128) {
    __syncthreads();
    const bf16_t* vrow = vb + (lr*256 + rbase)*HID + fc;
#pragma unroll
    for (int i = 0; i < 4; ++i) {
      const int p = lp0 + i;
      *(uint4*)&Vc[lr*128 + p*8] = *(const uint4*)&vrow[p*8];
    }
    __syncthreads();
    float vacc[32];
#pragma unroll
    for (int u = 0; u < 32; ++u) vacc[u] = 0.f;
    for (int s = 0; s < 64; ++s) {
      const float pp = E[s*64 + lane];
#pragma unroll
      for (int u = 0; u < 4; ++u) {
        bf16x8 vv = *(bf16x8*)&Vc[s*128 + wq_*32 + u*8];
#pragma unroll
        for (int t8 = 0; t8 < 8; ++t8) vacc[u*8 + t8] += pp * (float)vv[t8];
      }
    }
#pragma unroll
    for (int u = 0; u < 4; ++u) {
      bf16x8 ov;
#pragma unroll
      for (int t8 = 0; t8 < 8; ++t8) ov[t8] = (bf16_t)(vacc[u*8 + t8] * rv);
      *(bf16x8*)&ob[orow*HID + fc + wq_*32 + u*8] = ov;
    }
  }
}

// ---------------- global layer-norm: 2-stage reduce + normalize ------------
__global__ __launch_bounds__(256) void reduce1(const float* __restrict__ t,
                                               float* __restrict__ part, long n4)
{
  float s = 0.f, s2 = 0.f;
  for (long i = (long)blockIdx.x*blockDim.x + threadIdx.x; i < n4;
       i += (long)gridDim.x*blockDim.x) {
    float4 v = ((const float4*)t)[i];
    s  += v.x + v.y + v.z + v.w;
    s2 += v.x*v.x + v.y*v.y + v.z*v.z + v.w*v.w;
  }
  __shared__ float sh[256], sh2[256];
  const int tid = threadIdx.x;
  sh[tid] = s; sh2[tid] = s2; __syncthreads();
  for (int o = 128; o > 0; o >>= 1) {
    if (tid < o) { sh[tid] += sh[tid+o]; sh2[tid] += sh2[tid+o]; }
    __syncthreads();
  }
  if (tid == 0) { part[blockIdx.x] = sh[0]; part[2048 + blockIdx.x] = sh2[0]; }
}

__global__ __launch_bounds__(256) void reduce2(const float* __restrict__ part,
                                               float* __restrict__ stats)
{
  __shared__ double sh[256], sh2[256];
  const int tid = threadIdx.x;
  double s = 0.0, s2 = 0.0;
  for (int i = tid; i < 2048; i += 256) { s += part[i]; s2 += part[2048 + i]; }
  sh[tid] = s; sh2[tid] = s2; __syncthreads();
  for (int o = 128; o > 0; o >>= 1) {
    if (tid < o) { sh[tid] += sh[tid+o]; sh2[tid] += sh2[tid+o]; }
    __syncthreads();
  }
  if (tid == 0) {
    const double n = (double)NTOT;
    const double mean = sh[0] / n;
    const double var  = sh2[0] / n - mean*mean;
    stats[0] = (float)mean;
    stats[1] = (float)(1.0 / sqrt(var + 1e-5));
  }
}

__global__ __launch_bounds__(256) void ln_norm(const float* __restrict__ t,
    const float* __restrict__ stats, float* __restrict__ outF,
    bf16_t* __restrict__ outB, long n4)
{
  const float mean = stats[0], rstd = stats[1];
  for (long i = (long)blockIdx.x*blockDim.x + threadIdx.x; i < n4;
       i += (long)gridDim.x*blockDim.x) {
    float4 v = ((const float4*)t)[i];
    float4 o = {(v.x-mean)*rstd, (v.y-mean)*rstd, (v.z-mean)*rstd, (v.w-mean)*rstd};
    ((float4*)outF)[i] = o;
    bf16x4 ob = {(bf16_t)o.x, (bf16_t)o.y, (bf16_t)o.z, (bf16_t)o.w};
    ((bf16x4*)outB)[i] = ob;
  }
}

// ---------------------------------------------------------------------------
extern "C" void kernel_launch(void* const* d_in, const int* in_sizes, int n_in,
                              void* d_out, int out_size, void* d_ws, size_t ws_size,
                              hipStream_t stream)
{
  const int*   x    = (const int*)  d_in[0];
  const float* emb  = (const float*)d_in[1];
  const float* pos  = (const float*)d_in[2];
  const float* wq_a = (const float*)d_in[3];
  const float* bq_a = (const float*)d_in[4];
  const float* wk_a = (const float*)d_in[5];
  const float* bk_a = (const float*)d_in[6];
  const float* wv_a = (const float*)d_in[7];
  const float* bv_a = (const float*)d_in[8];
  const float* wo_a = (const float*)d_in[9];
  const float* bo_a = (const float*)d_in[10];
  const float* w1_a = (const float*)d_in[11];
  const float* b1_a = (const float*)d_in[12];
  const float* w2_a = (const float*)d_in[13];
  const float* b2_a = (const float*)d_in[14];

  char* p = (char*)d_ws;
  auto take = [&](size_t n) { char* r = p; p += (n + 255) & ~(size_t)255; return r; };
  float*  h    = (float*) take(NTOT*4);
  bf16_t* hb   = (bf16_t*)take(NTOT*2);
  bf16_t* U    = (bf16_t*)take((size_t)NROW*FFD*2);
  bf16_t* qb   = U;
  bf16_t* kb   = U + NTOT;
  bf16_t* vbuf = U + 2*NTOT;
  bf16_t* attb = U + 3*NTOT;
  bf16_t* ff1  = U;
  bf16_t* wT   = (bf16_t*)take((size_t)FFD*HID*2);
  float*  part = (float*) take(4096*4);
  float*  stats= (float*) take(256);

  const long n4 = NTOT / 4;
  const int gH  = (NROW/256)*(HID/256);                 // 256 blocks
  const int gF  = (NROW/256)*(FFD/256);                 // 1024 blocks

  embed_k<<<NROW, 256, 0, stream>>>(x, emb, pos, h, hb);

  for (int i = 0; i < 6; ++i) {
    const float* Wq = wq_a + (size_t)i*HID*HID;  const float* Bq = bq_a + (size_t)i*HID;
    const float* Wk = wk_a + (size_t)i*HID*HID;  const float* Bk = bk_a + (size_t)i*HID;
    const float* Wv = wv_a + (size_t)i*HID*HID;  const float* Bv = bv_a + (size_t)i*HID;
    const float* Wo = wo_a + (size_t)i*HID*HID;  const float* Bo = bo_a + (size_t)i*HID;
    const float* W1 = w1_a + (size_t)i*HID*FFD;  const float* B1 = b1_a + (size_t)i*FFD;
    const float* W2 = w2_a + (size_t)i*FFD*HID;  const float* B2 = b2_a + (size_t)i*HID;

    wcvt<<<(HID/32)*(HID/32), 256, 0, stream>>>(Wq, wT, HID, HID);
    gemm256<0><<<gH, 512, 0, stream>>>(hb, wT, Bq, nullptr, nullptr, qb, NROW, HID, HID);
    wcvt<<<(HID/32)*(HID/32), 256, 0, stream>>>(Wk, wT, HID, HID);
    gemm256<0><<<gH, 512, 0, stream>>>(hb, wT, Bk, nullptr, nullptr, kb, NROW, HID, HID);
    wcvt<<<(HID/32)*(HID/32), 256, 0, stream>>>(Wv, wT, HID, HID);
    gemm256<0><<<gH, 512, 0, stream>>>(hb, wT, Bv, nullptr, nullptr, vbuf, NROW, HID, HID);

    attn_k<<<256, 256, 0, stream>>>(qb, kb, vbuf, attb);

    wcvt<<<(HID/32)*(HID/32), 256, 0, stream>>>(Wo, wT, HID, HID);
    gemm256<2><<<gH, 512, 0, stream>>>(attb, wT, Bo, h, h, nullptr, NROW, HID, HID);

    reduce1<<<2048, 256, 0, stream>>>(h, part, n4);
    reduce2<<<1, 256, 0, stream>>>(part, stats);
    ln_norm<<<2048, 256, 0, stream>>>(h, stats, h, hb, n4);

    wcvt<<<(FFD/32)*(HID/32), 256, 0, stream>>>(W1, wT, HID, FFD);
    gemm256<1><<<gF, 512, 0, stream>>>(hb, wT, B1, nullptr, nullptr, ff1, NROW, FFD, HID);
    wcvt<<<(HID/32)*(FFD/32), 256, 0, stream>>>(W2, wT, FFD, HID);
    gemm256<2><<<gH, 512, 0, stream>>>(ff1, wT, B2, h, h, nullptr, NROW, HID, FFD);

    reduce1<<<2048, 256, 0, stream>>>(h, part, n4);
    reduce2<<<1, 256, 0, stream>>>(part, stats);
    ln_norm<<<2048, 256, 0, stream>>>(h, stats, (i == 5) ? (float*)d_out : h, hb, n4);
  }
}

// Round 5
// 4645.210 us; speedup vs baseline: 1.0252x; 1.0025x over previous
//
#include <hip/hip_runtime.h>
#include <hip/hip_bf16.h>
#include <stdint.h>

typedef __bf16 bf16_t;
typedef __bf16 bf16x8 __attribute__((ext_vector_type(8)));
typedef __bf16 bf16x4 __attribute__((ext_vector_type(4)));
typedef float  f32x4  __attribute__((ext_vector_type(4)));

#define SEQ   512
#define BATCH 32
#define HID   1024
#define FFD   4096
#define NROW  (SEQ*BATCH)          /* 16384 rows, layout [s][b][feat] */
#define NTOT  ((long)NROW*HID)     /* 16,777,216 */

typedef __attribute__((address_space(3))) uint32_t lds_u32;
typedef __attribute__((address_space(1))) const uint32_t glb_u32;

__device__ __forceinline__ void gload_lds16(const void* g, void* l) {
  glb_u32* gp = reinterpret_cast<glb_u32*>(reinterpret_cast<uintptr_t>(g));
  lds_u32* lp = reinterpret_cast<lds_u32*>(reinterpret_cast<uintptr_t>(l));
  __builtin_amdgcn_global_load_lds(gp, lp, 16, 0, 0);
}

#define BAR() asm volatile("s_barrier" ::: "memory")

// ---------------- embedding: h = emb[x]*32 + pos[s]; also bf16 copy --------
__global__ __launch_bounds__(256) void embed_k(const int* __restrict__ x,
    const float* __restrict__ emb, const float* __restrict__ pos,
    float* __restrict__ h, bf16_t* __restrict__ hb)
{
  const long row = blockIdx.x;           // row = s*32 + b
  const int  s   = (int)(row >> 5);
  const long idx = x[row];
  const int  t   = threadIdx.x;
  float4 e  = ((const float4*)(emb + idx*HID))[t];
  float4 pv = ((const float4*)(pos + (long)s*HID))[t];
  float4 o  = {e.x*32.f+pv.x, e.y*32.f+pv.y, e.z*32.f+pv.z, e.w*32.f+pv.w};
  ((float4*)(h + row*HID))[t] = o;
  bf16x4 ob = {(bf16_t)o.x, (bf16_t)o.y, (bf16_t)o.z, (bf16_t)o.w};
  *(bf16x4*)(hb + row*HID + (long)t*4) = ob;
}

// ------------- weight convert + transpose: wT[n][k] = bf16(w[k][n]) --------
__global__ __launch_bounds__(256) void wcvt(const float* __restrict__ w,
    bf16_t* __restrict__ wT, int K, int N)
{
  __shared__ float tile[32][33];
  const int tx = threadIdx.x & 31, ty = threadIdx.x >> 5;   // ty 0..7
  const int ntx = N >> 5;
  const int n0 = (blockIdx.x % ntx) << 5;
  const int k0 = (blockIdx.x / ntx) << 5;
#pragma unroll
  for (int i = 0; i < 4; ++i)
    tile[ty + i*8][tx] = w[(long)(k0 + ty + i*8)*N + n0 + tx];
  __syncthreads();
#pragma unroll
  for (int i = 0; i < 4; ++i)
    wT[(long)(n0 + ty + i*8)*K + k0 + tx] = (bf16_t)tile[tx][ty + i*8];
}

// ====== bf16 MFMA GEMM, 256x256, BK=64, 8 waves — faithful m201 8-phase ====
// C[M,N] = A[M,K] * Bt[N,K]^T (+bias)
// MODE 0: outB=bf16(acc+bias)  MODE 1: outB=bf16(relu(acc+bias))  MODE 2: outF=acc+bias+res
//
// Iter processes K-tiles T0=2i (dbuf0), T1=2i+1 (dbuf1), 4 phases each:
//   phN: {ds_reads for THIS phase's MFMA quadrant; stage 1 half-tile;
//         [lgkmcnt(8) if 12 reads]; s_barrier; lgkmcnt(0); setprio(1);
//         16 MFMA; setprio(0); s_barrier}
// Reads per phase {12,4,8,0}: ph0 af-lo+bf0, ph1 bf1, ph2 af-hi, ph3 none.
// Stage schedule (half freed by the phase whose closing barrier precedes):
//   ph0:T1:A1  ph1:T0+2:B0  ph2:T0+2:B1  ph3:T0+2:A0
//   ph4:T0+2:A1 ph5:T1+2:B0 ph6:T1+2:B1  ph7:T1+2:A0
// vmcnt(6) ONLY at end of ph3/ph7 (7 half-tiles=14 loads in flight, retire 4,
// leave 3 halves) — completes the next tile's buffer, never drains.
// Tail stages wrap (junk, never consumed); vmcnt(0) after loop.
template<int MODE>
__global__ __launch_bounds__(512, 2)
void gemm256(const bf16_t* __restrict__ A, const bf16_t* __restrict__ Bt,
             const float* bias, const float* res,
             float* __restrict__ outF, bf16_t* __restrict__ outB,
             int M, int N, int K)
{
  __shared__ bf16_t As[2][2][128][64];   // [dbuf][half][row][k]
  __shared__ bf16_t Bs[2][2][128][64];
  const int tid = threadIdx.x;
  const int w = tid >> 6, l = tid & 63;
  const int wm = w >> 2, wn = w & 3;     // wave owns rows wm*128..+127, col-frags wn*16

  // bijective XCD swizzle (m204)
  const int nbn = N >> 8;
  const int nwg = gridDim.x;
  const int q8 = nwg >> 3, r8 = nwg & 7;
  const int xcd = blockIdx.x & 7, bidx = blockIdx.x >> 3;
  const int wg = (xcd < r8 ? xcd*(q8+1) : r8*(q8+1) + (xcd-r8)*q8) + bidx;
  const long bm = wg / nbn, bn = wg % nbn;
  const long rA0 = bm << 8, rB0 = bn << 8;

  // staging: one half-tile (128 rows x 64 k) = 2 gload_lds16 per wave
  const int srow = tid >> 3;                         // 0..63
  const int scol = (((tid & 7) ^ (srow & 7)) << 3);  // swizzled src chunk (elems)

  const int fr = l & 15;                 // fragment row/col
  const int kq = l >> 4;                 // k-quarter 0..3

  f32x4 acc[8][4];
#pragma unroll
  for (int m = 0; m < 8; ++m)
#pragma unroll
    for (int n = 0; n < 4; ++n) acc[m][n] = (f32x4){0.f,0.f,0.f,0.f};

#define STG(G, r0, BUF, d, h, kt) do { \
    const long kb_ = (long)(kt)*64 + scol; \
    gload_lds16((G) + ((r0) + (h)*128 + srow)*(long)K + kb_,      (void*)&BUF[d][h][w*8][0]); \
    gload_lds16((G) + ((r0) + (h)*128 + 64 + srow)*(long)K + kb_, (void*)&BUF[d][h][64 + w*8][0]); \
  } while (0)

  // swizzled fragment read: within-half row rih, k-slab kk (0/1)
#define FRG(BUF, d, h, rih, kk) \
    (*(const bf16x8*)((const char*)&BUF[d][h][0][0] + (rih)*128 + \
                      ((((kk)*4 + kq) ^ ((rih) & 7)) << 4)))

  bf16x8 af[4][2], bf0[2][2], bf1[2][2];

#define RD_A(d, hm) do { \
    _Pragma("unroll") for (int mm = 0; mm < 4; ++mm) { \
      const int rih = (hm)*64 + mm*16 + fr; \
      af[mm][0] = FRG(As, d, wm, rih, 0); \
      af[mm][1] = FRG(As, d, wm, rih, 1); \
    } } while (0)
#define RD_B0(d) do { \
    _Pragma("unroll") for (int nn = 0; nn < 2; ++nn) { \
      const int rih = nn*64 + wn*16 + fr; \
      bf0[nn][0] = FRG(Bs, d, 0, rih, 0); \
      bf0[nn][1] = FRG(Bs, d, 0, rih, 1); \
    } } while (0)
#define RD_B1(d) do { \
    _Pragma("unroll") for (int nn = 0; nn < 2; ++nn) { \
      const int rih = nn*64 + wn*16 + fr; \
      bf1[nn][0] = FRG(Bs, d, 1, rih, 0); \
      bf1[nn][1] = FRG(Bs, d, 1, rih, 1); \
    } } while (0)
#define MFMA_Q(mh, BF, bh) do { \
    __builtin_amdgcn_s_setprio(1); \
    _Pragma("unroll") for (int mm = 0; mm < 4; ++mm) \
      _Pragma("unroll") for (int nn = 0; nn < 2; ++nn) \
        _Pragma("unroll") for (int kk = 0; kk < 2; ++kk) \
          acc[(mh)*4+mm][(bh)*2+nn] = __builtin_amdgcn_mfma_f32_16x16x32_bf16( \
              af[mm][kk], BF[nn][kk], acc[(mh)*4+mm][(bh)*2+nn], 0, 0, 0); \
    __builtin_amdgcn_s_setprio(0); \
  } while (0)

#define LGKM0() do { asm volatile("s_waitcnt lgkmcnt(0)" ::: "memory"); \
                     __builtin_amdgcn_sched_barrier(0); } while (0)

  const int nk = K >> 6;                 // even for all our K (16 or 64)
  const int iters = nk >> 1;

  // prologue: tile0 (4 halves, first 8 loads) then tile1 {B0,B1,A0} (6 loads)
  STG(A,  rA0, As, 0, 0, 0); STG(A,  rA0, As, 0, 1, 0);
  STG(Bt, rB0, Bs, 0, 0, 0); STG(Bt, rB0, Bs, 0, 1, 0);
  STG(Bt, rB0, Bs, 1, 0, 1); STG(Bt, rB0, Bs, 1, 1, 1);
  STG(A,  rA0, As, 1, 0, 1);
  asm volatile("s_waitcnt vmcnt(6)" ::: "memory");   // tile0 resident
  BAR();

  for (int i = 0; i < iters; ++i) {
    const int T1 = 2*i + 1;
    int ST0 = 2*i + 2; if (ST0 >= nk) ST0 -= nk;     // wrapped (tail junk)
    int ST1 = 2*i + 3; if (ST1 >= nk) ST1 -= nk;

    // ============ tile T0 (dbuf 0) ============
    // ph0
    RD_A(0, 0); RD_B0(0);
    STG(A, rA0, As, 1, 1, T1);
    asm volatile("s_waitcnt lgkmcnt(8)" ::: "memory");
    BAR(); LGKM0();
    MFMA_Q(0, bf0, 0);
    BAR();
    // ph1
    RD_B1(0);
    STG(Bt, rB0, Bs, 0, 0, ST0);
    BAR(); LGKM0();
    MFMA_Q(0, bf1, 1);
    BAR();
    // ph2
    RD_A(0, 1);
    STG(Bt, rB0, Bs, 0, 1, ST0);
    BAR(); LGKM0();
    MFMA_Q(1, bf0, 0);
    BAR();
    // ph3
    STG(A, rA0, As, 0, 0, ST0);
    BAR();
    MFMA_Q(1, bf1, 1);
    asm volatile("s_waitcnt vmcnt(6)" ::: "memory"); // tile T1 resident
    BAR();

    // ============ tile T1 (dbuf 1) ============
    // ph4
    RD_A(1, 0); RD_B0(1);
    STG(A, rA0, As, 0, 1, ST0);
    asm volatile("s_waitcnt lgkmcnt(8)" ::: "memory");
    BAR(); LGKM0();
    MFMA_Q(0, bf0, 0);
    BAR();
    // ph5
    RD_B1(1);
    STG(Bt, rB0, Bs, 1, 0, ST1);
    BAR(); LGKM0();
    MFMA_Q(0, bf1, 1);
    BAR();
    // ph6
    RD_A(1, 1);
    STG(Bt, rB0, Bs, 1, 1, ST1);
    BAR(); LGKM0();
    MFMA_Q(1, bf0, 0);
    BAR();
    // ph7
    STG(A, rA0, As, 1, 0, ST1);
    BAR();
    MFMA_Q(1, bf1, 1);
    asm volatile("s_waitcnt vmcnt(6)" ::: "memory"); // tile T0+2 resident
    BAR();
  }
  asm volatile("s_waitcnt vmcnt(0)" ::: "memory");   // drain tail junk loads
#undef STG
#undef FRG
#undef RD_A
#undef RD_B0
#undef RD_B1
#undef MFMA_Q
#undef LGKM0

  // epilogue — launder pointers so vmem loads can't hoist into the loop
  uintptr_t bp = (uintptr_t)bias;  asm volatile("" : "+v"(bp));
  uintptr_t rp = (uintptr_t)res;   asm volatile("" : "+v"(rp));
  const float* biasq = (const float*)bp;
  const float* resq  = (const float*)rp;
  const int er = (l >> 4) << 2;
#pragma unroll
  for (int n = 0; n < 4; ++n) {
    const long col = rB0 + (n >> 1)*128 + (n & 1)*64 + wn*16 + fr;
    const float bv = biasq[col];
#pragma unroll
    for (int m = 0; m < 8; ++m) {
      const long row0 = rA0 + wm*128 + m*16 + er;
#pragma unroll
      for (int j = 0; j < 4; ++j) {
        const long off = (row0 + j)*(long)N + col;
        const float v = acc[m][n][j] + bv;
        if (MODE == 0)      outB[off] = (bf16_t)v;
        else if (MODE == 1) outB[off] = (bf16_t)fmaxf(v, 0.f);
        else                outF[off] = v + resq[off];
      }
    }
  }
}

// ---------------- attention: one block per (b, head) -----------------------
__global__ __launch_bounds__(256) void attn_k(
    const bf16_t* __restrict__ qb, const bf16_t* __restrict__ kb,
    const bf16_t* __restrict__ vb, bf16_t* __restrict__ ob)
{
  __shared__ __align__(16) char smem[64*128*2*2 + 64*64*4 + 64*4];
  bf16_t* Qc = (bf16_t*)smem;
  bf16_t* Kc = (bf16_t*)(smem + 16384);
  bf16_t* Vc = (bf16_t*)smem;                  // aliases Qc (phase-disjoint)
  float*  E    = (float*)(smem + 32768);
  float*  Rinv = (float*)(smem + 49152);

  const int tid  = threadIdx.x;
  const int head = blockIdx.x & 7, b = blockIdx.x >> 3;
  const long rbase = (long)head*32 + b;

  const int ti = tid >> 2, g = tid & 3;
  const int lr  = tid >> 2;
  const int lp0 = (tid & 3) * 4;

  float eacc[16];
#pragma unroll
  for (int j = 0; j < 16; ++j) eacc[j] = 0.f;

  for (int kc = 0; kc < HID; kc += 128) {
    __syncthreads();
    const bf16_t* qrow = qb + (lr*256 + rbase)*HID + kc;
    const bf16_t* krow = kb + (lr*256 + rbase)*HID + kc;
#pragma unroll
    for (int i = 0; i < 4; ++i) {
      const int p = lp0 + i;
      const int src = (p ^ (lr & 7)) * 8;
      *(uint4*)&Qc[lr*128 + p*8] = *(const uint4*)&qrow[src];
      *(uint4*)&Kc[lr*128 + p*8] = *(const uint4*)&krow[src];
    }
    __syncthreads();
    for (int e8 = 0; e8 < 16; ++e8) {
      const int qp = e8 ^ (ti & 7);
      bf16x8 qv = *(bf16x8*)&Qc[ti*128 + qp*8];
      float qf[8];
#pragma unroll
      for (int u = 0; u < 8; ++u) qf[u] = (float)qv[u];
#pragma unroll
      for (int j = 0; j < 16; ++j) {
        const int s  = j*4 + g;
        const int kp = e8 ^ (s & 7);
        bf16x8 kv = *(bf16x8*)&Kc[s*128 + kp*8];
        float a = eacc[j];
#pragma unroll
        for (int u = 0; u < 8; ++u) a += qf[u] * (float)kv[u];
        eacc[j] = a;
      }
    }
  }
  const float scale = 0.0883883476483184f;     // 1/sqrt(128)
  float mx = -1e30f;
#pragma unroll
  for (int j = 0; j < 16; ++j) { eacc[j] *= scale; mx = fmaxf(mx, eacc[j]); }
  mx = fmaxf(mx, __shfl_xor(mx, 1));
  mx = fmaxf(mx, __shfl_xor(mx, 2));
  float sum = 0.f;
#pragma unroll
  for (int j = 0; j < 16; ++j) {
    const float pj = __expf(eacc[j] - mx);
    E[(j*4 + g)*64 + ti] = pj;
    sum += pj;
  }
  sum += __shfl_xor(sum, 1);
  sum += __shfl_xor(sum, 2);
  if (g == 0) Rinv[ti] = 1.f / sum;
  __syncthreads();

  const int lane = tid & 63, wq_ = tid >> 6;
  const float rv = Rinv[lane];
  const long orow = (long)lane*256 + b*8 + head;
  for (int fc = 0; fc < HID; fc += 128) {
    __syncthreads();
    const bf16_t* vrow = vb + (lr*256 + rbase)*HID + fc;
#pragma unroll
    for (int i = 0; i < 4; ++i) {
      const int p = lp0 + i;
      *(uint4*)&Vc[lr*128 + p*8] = *(const uint4*)&vrow[p*8];
    }
    __syncthreads();
    float vacc[32];
#pragma unroll
    for (int u = 0; u < 32; ++u) vacc[u] = 0.f;
    for (int s = 0; s < 64; ++s) {
      const float pp = E[s*64 + lane];
#pragma unroll
      for (int u = 0; u < 4; ++u) {
        bf16x8 vv = *(bf16x8*)&Vc[s*128 + wq_*32 + u*8];
#pragma unroll
        for (int t8 = 0; t8 < 8; ++t8) vacc[u*8 + t8] += pp * (float)vv[t8];
      }
    }
#pragma unroll
    for (int u = 0; u < 4; ++u) {
      bf16x8 ov;
#pragma unroll
      for (int t8 = 0; t8 < 8; ++t8) ov[t8] = (bf16_t)(vacc[u*8 + t8] * rv);
      *(bf16x8*)&ob[orow*HID + fc + wq_*32 + u*8] = ov;
    }
  }
}

// ---------------- global layer-norm: 2-stage reduce + normalize ------------
__global__ __launch_bounds__(256) void reduce1(const float* __restrict__ t,
                                               float* __restrict__ part, long n4)
{
  float s = 0.f, s2 = 0.f;
  for (long i = (long)blockIdx.x*blockDim.x + threadIdx.x; i < n4;
       i += (long)gridDim.x*blockDim.x) {
    float4 v = ((const float4*)t)[i];
    s  += v.x + v.y + v.z + v.w;
    s2 += v.x*v.x + v.y*v.y + v.z*v.z + v.w*v.w;
  }
  __shared__ float sh[256], sh2[256];
  const int tid = threadIdx.x;
  sh[tid] = s; sh2[tid] = s2; __syncthreads();
  for (int o = 128; o > 0; o >>= 1) {
    if (tid < o) { sh[tid] += sh[tid+o]; sh2[tid] += sh2[tid+o]; }
    __syncthreads();
  }
  if (tid == 0) { part[blockIdx.x] = sh[0]; part[2048 + blockIdx.x] = sh2[0]; }
}

__global__ __launch_bounds__(256) void reduce2(const float* __restrict__ part,
                                               float* __restrict__ stats)
{
  __shared__ double sh[256], sh2[256];
  const int tid = threadIdx.x;
  double s = 0.0, s2 = 0.0;
  for (int i = tid; i < 2048; i += 256) { s += part[i]; s2 += part[2048 + i]; }
  sh[tid] = s; sh2[tid] = s2; __syncthreads();
  for (int o = 128; o > 0; o >>= 1) {
    if (tid < o) { sh[tid] += sh[tid+o]; sh2[tid] += sh2[tid+o]; }
    __syncthreads();
  }
  if (tid == 0) {
    const double n = (double)NTOT;
    const double mean = sh[0] / n;
    const double var  = sh2[0] / n - mean*mean;
    stats[0] = (float)mean;
    stats[1] = (float)(1.0 / sqrt(var + 1e-5));
  }
}

__global__ __launch_bounds__(256) void ln_norm(const float* __restrict__ t,
    const float* __restrict__ stats, float* __restrict__ outF,
    bf16_t* __restrict__ outB, long n4)
{
  const float mean = stats[0], rstd = stats[1];
  for (long i = (long)blockIdx.x*blockDim.x + threadIdx.x; i < n4;
       i += (long)gridDim.x*blockDim.x) {
    float4 v = ((const float4*)t)[i];
    float4 o = {(v.x-mean)*rstd, (v.y-mean)*rstd, (v.z-mean)*rstd, (v.w-mean)*rstd};
    ((float4*)outF)[i] = o;
    bf16x4 ob = {(bf16_t)o.x, (bf16_t)o.y, (bf16_t)o.z, (bf16_t)o.w};
    ((bf16x4*)outB)[i] = ob;
  }
}

// ---------------------------------------------------------------------------
extern "C" void kernel_launch(void* const* d_in, const int* in_sizes, int n_in,
                              void* d_out, int out_size, void* d_ws, size_t ws_size,
                              hipStream_t stream)
{
  const int*   x    = (const int*)  d_in[0];
  const float* emb  = (const float*)d_in[1];
  const float* pos  = (const float*)d_in[2];
  const float* wq_a = (const float*)d_in[3];
  const float* bq_a = (const float*)d_in[4];
  const float* wk_a = (const float*)d_in[5];
  const float* bk_a = (const float*)d_in[6];
  const float* wv_a = (const float*)d_in[7];
  const float* bv_a = (const float*)d_in[8];
  const float* wo_a = (const float*)d_in[9];
  const float* bo_a = (const float*)d_in[10];
  const float* w1_a = (const float*)d_in[11];
  const float* b1_a = (const float*)d_in[12];
  const float* w2_a = (const float*)d_in[13];
  const float* b2_a = (const float*)d_in[14];

  char* p = (char*)d_ws;
  auto take = [&](size_t n) { char* r = p; p += (n + 255) & ~(size_t)255; return r; };
  float*  h    = (float*) take(NTOT*4);
  bf16_t* hb   = (bf16_t*)take(NTOT*2);
  bf16_t* U    = (bf16_t*)take((size_t)NROW*FFD*2);
  bf16_t* qb   = U;
  bf16_t* kb   = U + NTOT;
  bf16_t* vbuf = U + 2*NTOT;
  bf16_t* attb = U + 3*NTOT;
  bf16_t* ff1  = U;
  bf16_t* wT   = (bf16_t*)take((size_t)FFD*HID*2);
  float*  part = (float*) take(4096*4);
  float*  stats= (float*) take(256);

  const long n4 = NTOT / 4;
  const int gH  = (NROW/256)*(HID/256);                 // 256 blocks
  const int gF  = (NROW/256)*(FFD/256);                 // 1024 blocks

  embed_k<<<NROW, 256, 0, stream>>>(x, emb, pos, h, hb);

  for (int i = 0; i < 6; ++i) {
    const float* Wq = wq_a + (size_t)i*HID*HID;  const float* Bq = bq_a + (size_t)i*HID;
    const float* Wk = wk_a + (size_t)i*HID*HID;  const float* Bk = bk_a + (size_t)i*HID;
    const float* Wv = wv_a + (size_t)i*HID*HID;  const float* Bv = bv_a + (size_t)i*HID;
    const float* Wo = wo_a + (size_t)i*HID*HID;  const float* Bo = bo_a + (size_t)i*HID;
    const float* W1 = w1_a + (size_t)i*HID*FFD;  const float* B1 = b1_a + (size_t)i*FFD;
    const float* W2 = w2_a + (size_t)i*FFD*HID;  const float* B2 = b2_a + (size_t)i*HID;

    wcvt<<<(HID/32)*(HID/32), 256, 0, stream>>>(Wq, wT, HID, HID);
    gemm256<0><<<gH, 512, 0, stream>>>(hb, wT, Bq, nullptr, nullptr, qb, NROW, HID, HID);
    wcvt<<<(HID/32)*(HID/32), 256, 0, stream>>>(Wk, wT, HID, HID);
    gemm256<0><<<gH, 512, 0, stream>>>(hb, wT, Bk, nullptr, nullptr, kb, NROW, HID, HID);
    wcvt<<<(HID/32)*(HID/32), 256, 0, stream>>>(Wv, wT, HID, HID);
    gemm256<0><<<gH, 512, 0, stream>>>(hb, wT, Bv, nullptr, nullptr, vbuf, NROW, HID, HID);

    attn_k<<<256, 256, 0, stream>>>(qb, kb, vbuf, attb);

    wcvt<<<(HID/32)*(HID/32), 256, 0, stream>>>(Wo, wT, HID, HID);
    gemm256<2><<<gH, 512, 0, stream>>>(attb, wT, Bo, h, h, nullptr, NROW, HID, HID);

    reduce1<<<2048, 256, 0, stream>>>(h, part, n4);
    reduce2<<<1, 256, 0, stream>>>(part, stats);
    ln_norm<<<2048, 256, 0, stream>>>(h, stats, h, hb, n4);

    wcvt<<<(FFD/32)*(HID/32), 256, 0, stream>>>(W1, wT, HID, FFD);
    gemm256<1><<<gF, 512, 0, stream>>>(hb, wT, B1, nullptr, nullptr, ff1, NROW, FFD, HID);
    wcvt<<<(HID/32)*(FFD/32), 256, 0, stream>>>(W2, wT, FFD, HID);
    gemm256<2><<<gH, 512, 0, stream>>>(ff1, wT, B2, h, h, nullptr, NROW, HID, FFD);

    reduce1<<<2048, 256, 0, stream>>>(h, part, n4);
    reduce2<<<1, 256, 0, stream>>>(part, stats);
    ln_norm<<<2048, 256, 0, stream>>>(h, stats, (i == 5) ? (float*)d_out : h, hb, n4);
  }
}

// Round 6
// 4338.140 us; speedup vs baseline: 1.0978x; 1.0708x over previous
//
#include <hip/hip_runtime.h>
#include <hip/hip_bf16.h>
#include <stdint.h>

typedef __bf16 bf16_t;
typedef __bf16 bf16x8 __attribute__((ext_vector_type(8)));
typedef __bf16 bf16x4 __attribute__((ext_vector_type(4)));
typedef float  f32x16 __attribute__((ext_vector_type(16)));

#define SEQ   512
#define BATCH 32
#define HID   1024
#define FFD   4096
#define NROW  (SEQ*BATCH)          /* 16384 rows, layout [s][b][feat] */
#define NTOT  ((long)NROW*HID)     /* 16,777,216 */

typedef __attribute__((address_space(3))) uint32_t lds_u32;
typedef __attribute__((address_space(1))) const uint32_t glb_u32;

__device__ __forceinline__ void gload_lds16(const void* g, void* l) {
  glb_u32* gp = reinterpret_cast<glb_u32*>(reinterpret_cast<uintptr_t>(g));
  lds_u32* lp = reinterpret_cast<lds_u32*>(reinterpret_cast<uintptr_t>(l));
  __builtin_amdgcn_global_load_lds(gp, lp, 16, 0, 0);
}

// ---------------- embedding: h = emb[x]*32 + pos[s]; also bf16 copy --------
__global__ __launch_bounds__(256) void embed_k(const int* __restrict__ x,
    const float* __restrict__ emb, const float* __restrict__ pos,
    float* __restrict__ h, bf16_t* __restrict__ hb)
{
  const long row = blockIdx.x;           // row = s*32 + b
  const int  s   = (int)(row >> 5);
  const long idx = x[row];
  const int  t   = threadIdx.x;
  float4 e  = ((const float4*)(emb + idx*HID))[t];
  float4 pv = ((const float4*)(pos + (long)s*HID))[t];
  float4 o  = {e.x*32.f+pv.x, e.y*32.f+pv.y, e.z*32.f+pv.z, e.w*32.f+pv.w};
  ((float4*)(h + row*HID))[t] = o;
  bf16x4 ob = {(bf16_t)o.x, (bf16_t)o.y, (bf16_t)o.z, (bf16_t)o.w};
  *(bf16x4*)(hb + row*HID + (long)t*4) = ob;
}

// ------------- weight convert + transpose: wT[n][k] = bf16(w[k][n]) --------
__device__ __forceinline__ void wcvt_body(const float* __restrict__ w,
    bf16_t* __restrict__ wT, int K, int N, int bid)
{
  __shared__ float tile[32][33];
  const int tx = threadIdx.x & 31, ty = threadIdx.x >> 5;   // ty 0..7
  const int ntx = N >> 5;
  const int n0 = (bid % ntx) << 5;
  const int k0 = (bid / ntx) << 5;
#pragma unroll
  for (int i = 0; i < 4; ++i)
    tile[ty + i*8][tx] = w[(long)(k0 + ty + i*8)*N + n0 + tx];
  __syncthreads();
#pragma unroll
  for (int i = 0; i < 4; ++i)
    wT[(long)(n0 + ty + i*8)*K + k0 + tx] = (bf16_t)tile[tx][ty + i*8];
}

__global__ __launch_bounds__(256) void wcvt(const float* __restrict__ w,
    bf16_t* __restrict__ wT, int K, int N)
{
  wcvt_body(w, wT, K, N, blockIdx.x);
}

// merged Q/K/V convert into wT3[3072][1024]
__global__ __launch_bounds__(256) void wcvt3(const float* __restrict__ wq,
    const float* __restrict__ wk, const float* __restrict__ wv,
    bf16_t* __restrict__ wT3)
{
  const int sel = blockIdx.x >> 10;          // 1024 blocks per source
  const int bid = blockIdx.x & 1023;
  const float* w = sel == 0 ? wq : sel == 1 ? wk : wv;
  wcvt_body(w, wT3 + (size_t)sel*HID*HID, HID, HID, bid);
}

// concat bias: bias3 = [bq | bk | bv]
__global__ __launch_bounds__(256) void catb(const float* __restrict__ a,
    const float* __restrict__ b, const float* __restrict__ c,
    float* __restrict__ o)
{
  const float* s = blockIdx.x == 0 ? a : blockIdx.x == 1 ? b : c;
  ((float4*)(o + blockIdx.x*1024))[threadIdx.x] = ((const float4*)s)[threadIdx.x];
}

// ====== bf16 MFMA GEMM, 128x256 tile, BK=64, 8 waves, 32x32x16 shape =======
// C[M,N] = A[M,K] * Bt[N,K]^T (+bias)
// MODE 0: outB=bf16(acc+bias)  MODE 1: outB=bf16(relu(acc+bias))
// MODE 2: outF=acc+bias+res, and per-block LN partials (sum,sumsq) -> part
// Single-buffered LDS (52 KB) + __syncthreads drain (m97 pattern); 2 blocks/CU
// co-resident provide the overlap (m114 mechanism). Wave grid 2m x 4n, wave
// tile 64x64 = 2x2 MFMA tiles of 32x32, acc = 4 x f32x16.
template<int MODE>
__global__ __launch_bounds__(512, 4)
void gemmW(const bf16_t* __restrict__ A, const bf16_t* __restrict__ Bt,
           const float* bias, const float* res,
           float* __restrict__ outF, bf16_t* __restrict__ outB,
           float* __restrict__ part, int M, int N, int K)
{
  __shared__ bf16_t As[128][64];
  __shared__ bf16_t Bs[256][64];
  __shared__ float  rs[512], rq[512];
  const int tid = threadIdx.x;
  const int w = tid >> 6, l = tid & 63;
  const int wm = w >> 2, wn = w & 3;      // wave tile: rows wm*64, cols wn*64
  const int lr = l & 31, hi = l >> 5;

  // bijective XCD swizzle (m204)
  const int nbn = N >> 8;
  const int nwg = gridDim.x;
  const int q8 = nwg >> 3, r8 = nwg & 7;
  const int xcd = blockIdx.x & 7, bidx = blockIdx.x >> 3;
  const int wg = (xcd < r8 ? xcd*(q8+1) : r8*(q8+1) + (xcd-r8)*q8) + bidx;
  const long bm = wg / nbn, bn = wg % nbn;
  const long rA0 = bm << 7, rB0 = bn << 8;

  // staging: thread t covers LDS slot row=(t>>3)+i*64, chunk=t&7 (16B chunks)
  const int srow   = tid >> 3;                               // 0..63
  const int schunk = (((tid & 7) ^ ((tid >> 3) & 7)) << 3);  // swizzled src col
  const int ldsw   = (tid >> 6) << 10;                       // wave-uniform dest

  f32x16 a00 = {0}, a01 = {0}, a10 = {0}, a11 = {0};

#define STG_TILE(kt) do { \
    const long kb_ = (long)(kt)*64 + schunk; \
    gload_lds16(A  + (rA0 + srow)*(long)K + kb_,        (char*)As + ldsw); \
    gload_lds16(A  + (rA0 + 64 + srow)*(long)K + kb_,   (char*)As + 8192 + ldsw); \
    gload_lds16(Bt + (rB0 + srow)*(long)K + kb_,        (char*)Bs + ldsw); \
    gload_lds16(Bt + (rB0 + 64 + srow)*(long)K + kb_,   (char*)Bs + 8192 + ldsw); \
    gload_lds16(Bt + (rB0 + 128 + srow)*(long)K + kb_,  (char*)Bs + 16384 + ldsw); \
    gload_lds16(Bt + (rB0 + 192 + srow)*(long)K + kb_,  (char*)Bs + 24576 + ldsw); \
  } while (0)

  // frag read: row r (within As/Bs), k-slab kk (0..3): chunk (kk*2+hi)^(r&7)
#define FRA(mt, kk) (*(const bf16x8*)((const char*)As + (wm*64 + (mt)*32 + lr)*128 + \
                      ((((kk)*2 + hi) ^ (l & 7)) << 4)))
#define FRB(nt, kk) (*(const bf16x8*)((const char*)Bs + (wn*64 + (nt)*32 + lr)*128 + \
                      ((((kk)*2 + hi) ^ (l & 7)) << 4)))

  const int nk = K >> 6;
  for (int t = 0; t < nk; ++t) {
    __syncthreads();                       // prior tile fully consumed
    STG_TILE(t);
    __syncthreads();                       // full drain (compiler emits vmcnt0)
#pragma unroll
    for (int kk = 0; kk < 4; ++kk) {
      bf16x8 fa0 = FRA(0, kk), fa1 = FRA(1, kk);
      bf16x8 fb0 = FRB(0, kk), fb1 = FRB(1, kk);
      a00 = __builtin_amdgcn_mfma_f32_32x32x16_bf16(fa0, fb0, a00, 0, 0, 0);
      a01 = __builtin_amdgcn_mfma_f32_32x32x16_bf16(fa0, fb1, a01, 0, 0, 0);
      a10 = __builtin_amdgcn_mfma_f32_32x32x16_bf16(fa1, fb0, a10, 0, 0, 0);
      a11 = __builtin_amdgcn_mfma_f32_32x32x16_bf16(fa1, fb1, a11, 0, 0, 0);
    }
  }
#undef STG_TILE
#undef FRA
#undef FRB

  // epilogue. 32x32 C/D layout: col=lane&31, row=(r&3)+8*(r>>2)+4*(lane>>5)
  float ls = 0.f, lsq = 0.f;
  const long rowT = rA0 + wm*64 + 4*hi;
  const long colT = rB0 + wn*64 + lr;
#pragma unroll
  for (int nt = 0; nt < 2; ++nt) {
    const long col = colT + nt*32;
    const float bv = bias[col];
#pragma unroll
    for (int mt = 0; mt < 2; ++mt) {
      const f32x16 acc = mt == 0 ? (nt == 0 ? a00 : a01) : (nt == 0 ? a10 : a11);
#pragma unroll
      for (int r = 0; r < 16; ++r) {
        const long row = rowT + mt*32 + (r & 3) + 8*(r >> 2);
        const long off = row*(long)N + col;
        float v = acc[r] + bv;
        if (MODE == 0)      outB[off] = (bf16_t)v;
        else if (MODE == 1) outB[off] = (bf16_t)fmaxf(v, 0.f);
        else {
          v += res[off];
          outF[off] = v;
          ls += v; lsq += v*v;
        }
      }
    }
  }
  if (MODE == 2) {                         // block-local LN partials
    rs[tid] = ls; rq[tid] = lsq;
    __syncthreads();
    for (int o = 256; o > 0; o >>= 1) {
      if (tid < o) { rs[tid] += rs[tid+o]; rq[tid] += rq[tid+o]; }
      __syncthreads();
    }
    if (tid == 0) { part[2*blockIdx.x] = rs[0]; part[2*blockIdx.x + 1] = rq[0]; }
  }
}

// ---------------- attention: one block per (b, head) -----------------------
// q/k/v are columns 0/1024/2048 of the fused qkv buffer (row stride 3072)
#define QKVS 3072
__global__ __launch_bounds__(256) void attn_k(
    const bf16_t* __restrict__ qkv, bf16_t* __restrict__ ob)
{
  __shared__ __align__(16) char smem[64*128*2*2 + 64*64*4 + 64*4];
  bf16_t* Qc = (bf16_t*)smem;
  bf16_t* Kc = (bf16_t*)(smem + 16384);
  bf16_t* Vc = (bf16_t*)smem;                  // aliases Qc (phase-disjoint)
  float*  E    = (float*)(smem + 32768);
  float*  Rinv = (float*)(smem + 49152);

  const int tid  = threadIdx.x;
  const int head = blockIdx.x & 7, b = blockIdx.x >> 3;
  const long rbase = (long)head*32 + b;

  const int ti = tid >> 2, g = tid & 3;
  const int lr  = tid >> 2;
  const int lp0 = (tid & 3) * 4;

  float eacc[16];
#pragma unroll
  for (int j = 0; j < 16; ++j) eacc[j] = 0.f;

  for (int kc = 0; kc < HID; kc += 128) {
    __syncthreads();
    const bf16_t* qrow = qkv + (lr*256 + rbase)*QKVS + kc;
    const bf16_t* krow = qkv + (lr*256 + rbase)*QKVS + 1024 + kc;
#pragma unroll
    for (int i = 0; i < 4; ++i) {
      const int p = lp0 + i;
      const int src = (p ^ (lr & 7)) * 8;
      *(uint4*)&Qc[lr*128 + p*8] = *(const uint4*)&qrow[src];
      *(uint4*)&Kc[lr*128 + p*8] = *(const uint4*)&krow[src];
    }
    __syncthreads();
    for (int e8 = 0; e8 < 16; ++e8) {
      const int qp = e8 ^ (ti & 7);
      bf16x8 qv = *(bf16x8*)&Qc[ti*128 + qp*8];
      float qf[8];
#pragma unroll
      for (int u = 0; u < 8; ++u) qf[u] = (float)qv[u];
#pragma unroll
      for (int j = 0; j < 16; ++j) {
        const int s  = j*4 + g;
        const int kp = e8 ^ (s & 7);
        bf16x8 kv = *(bf16x8*)&Kc[s*128 + kp*8];
        float a = eacc[j];
#pragma unroll
        for (int u = 0; u < 8; ++u) a += qf[u] * (float)kv[u];
        eacc[j] = a;
      }
    }
  }
  const float scale = 0.0883883476483184f;     // 1/sqrt(128)
  float mx = -1e30f;
#pragma unroll
  for (int j = 0; j < 16; ++j) { eacc[j] *= scale; mx = fmaxf(mx, eacc[j]); }
  mx = fmaxf(mx, __shfl_xor(mx, 1));
  mx = fmaxf(mx, __shfl_xor(mx, 2));
  float sum = 0.f;
#pragma unroll
  for (int j = 0; j < 16; ++j) {
    const float pj = __expf(eacc[j] - mx);
    E[(j*4 + g)*64 + ti] = pj;
    sum += pj;
  }
  sum += __shfl_xor(sum, 1);
  sum += __shfl_xor(sum, 2);
  if (g == 0) Rinv[ti] = 1.f / sum;
  __syncthreads();

  const int lane = tid & 63, wq_ = tid >> 6;
  const float rv = Rinv[lane];
  const long orow = (long)lane*256 + b*8 + head;
  for (int fc = 0; fc < HID; fc += 128) {
    __syncthreads();
    const bf16_t* vrow = qkv + (lr*256 + rbase)*QKVS + 2048 + fc;
#pragma unroll
    for (int i = 0; i < 4; ++i) {
      const int p = lp0 + i;
      *(uint4*)&Vc[lr*128 + p*8] = *(const uint4*)&vrow[p*8];
    }
    __syncthreads();
    float vacc[32];
#pragma unroll
    for (int u = 0; u < 32; ++u) vacc[u] = 0.f;
    for (int s = 0; s < 64; ++s) {
      const float pp = E[s*64 + lane];
#pragma unroll
      for (int u = 0; u < 4; ++u) {
        bf16x8 vv = *(bf16x8*)&Vc[s*128 + wq_*32 + u*8];
#pragma unroll
        for (int t8 = 0; t8 < 8; ++t8) vacc[u*8 + t8] += pp * (float)vv[t8];
      }
    }
#pragma unroll
    for (int u = 0; u < 4; ++u) {
      bf16x8 ov;
#pragma unroll
      for (int t8 = 0; t8 < 8; ++t8) ov[t8] = (bf16_t)(vacc[u*8 + t8] * rv);
      *(bf16x8*)&ob[orow*HID + fc + wq_*32 + u*8] = ov;
    }
  }
}

// -------- LN stage 2: sum per-block partials (np pairs) -> mean/rstd -------
__global__ __launch_bounds__(256) void reduce2(const float* __restrict__ part,
                                               float* __restrict__ stats, int np)
{
  __shared__ double sh[256], sh2[256];
  const int tid = threadIdx.x;
  double s = 0.0, s2 = 0.0;
  for (int i = tid; i < np; i += 256) { s += part[2*i]; s2 += part[2*i + 1]; }
  sh[tid] = s; sh2[tid] = s2; __syncthreads();
  for (int o = 128; o > 0; o >>= 1) {
    if (tid < o) { sh[tid] += sh[tid+o]; sh2[tid] += sh2[tid+o]; }
    __syncthreads();
  }
  if (tid == 0) {
    const double n = (double)NTOT;
    const double mean = sh[0] / n;
    const double var  = sh2[0] / n - mean*mean;
    stats[0] = (float)mean;
    stats[1] = (float)(1.0 / sqrt(var + 1e-5));
  }
}

__global__ __launch_bounds__(256) void ln_norm(const float* __restrict__ t,
    const float* __restrict__ stats, float* __restrict__ outF,
    bf16_t* __restrict__ outB, long n4)
{
  const float mean = stats[0], rstd = stats[1];
  for (long i = (long)blockIdx.x*blockDim.x + threadIdx.x; i < n4;
       i += (long)gridDim.x*blockDim.x) {
    float4 v = ((const float4*)t)[i];
    float4 o = {(v.x-mean)*rstd, (v.y-mean)*rstd, (v.z-mean)*rstd, (v.w-mean)*rstd};
    ((float4*)outF)[i] = o;
    bf16x4 ob = {(bf16_t)o.x, (bf16_t)o.y, (bf16_t)o.z, (bf16_t)o.w};
    ((bf16x4*)outB)[i] = ob;
  }
}

// ---------------------------------------------------------------------------
extern "C" void kernel_launch(void* const* d_in, const int* in_sizes, int n_in,
                              void* d_out, int out_size, void* d_ws, size_t ws_size,
                              hipStream_t stream)
{
  const int*   x    = (const int*)  d_in[0];
  const float* emb  = (const float*)d_in[1];
  const float* pos  = (const float*)d_in[2];
  const float* wq_a = (const float*)d_in[3];
  const float* bq_a = (const float*)d_in[4];
  const float* wk_a = (const float*)d_in[5];
  const float* bk_a = (const float*)d_in[6];
  const float* wv_a = (const float*)d_in[7];
  const float* bv_a = (const float*)d_in[8];
  const float* wo_a = (const float*)d_in[9];
  const float* bo_a = (const float*)d_in[10];
  const float* w1_a = (const float*)d_in[11];
  const float* b1_a = (const float*)d_in[12];
  const float* w2_a = (const float*)d_in[13];
  const float* b2_a = (const float*)d_in[14];

  char* p = (char*)d_ws;
  auto take = [&](size_t n) { char* r = p; p += (n + 255) & ~(size_t)255; return r; };
  float*  h    = (float*) take(NTOT*4);                 // 64 MB
  bf16_t* hb   = (bf16_t*)take(NTOT*2);                 // 32 MB
  bf16_t* U    = (bf16_t*)take((size_t)NROW*FFD*2);     // 128 MB union
  bf16_t* qkv  = U;                                     // 96 MB (NROW x 3072)
  bf16_t* attb = U + 3*NTOT;                            // 32 MB
  bf16_t* ff1  = U;                                     // overlays qkv (dead)
  bf16_t* wT   = (bf16_t*)take((size_t)FFD*HID*2);      // 8 MB
  bf16_t* wT3  = (bf16_t*)take((size_t)3*HID*HID*2);    // 6 MB
  float*  b3   = (float*) take(3072*4);
  float*  part = (float*) take(4096*4);
  float*  stats= (float*) take(256);

  const long n4 = NTOT / 4;

  embed_k<<<NROW, 256, 0, stream>>>(x, emb, pos, h, hb);

  for (int i = 0; i < 6; ++i) {
    const float* Wq = wq_a + (size_t)i*HID*HID;  const float* Bq = bq_a + (size_t)i*HID;
    const float* Wk = wk_a + (size_t)i*HID*HID;  const float* Bk = bk_a + (size_t)i*HID;
    const float* Wv = wv_a + (size_t)i*HID*HID;  const float* Bv = bv_a + (size_t)i*HID;
    const float* Wo = wo_a + (size_t)i*HID*HID;  const float* Bo = bo_a + (size_t)i*HID;
    const float* W1 = w1_a + (size_t)i*HID*FFD;  const float* B1 = b1_a + (size_t)i*FFD;
    const float* W2 = w2_a + (size_t)i*FFD*HID;  const float* B2 = b2_a + (size_t)i*HID;

    // fused QKV projection (N = 3072)
    wcvt3<<<3072, 256, 0, stream>>>(Wq, Wk, Wv, wT3);
    catb<<<3, 256, 0, stream>>>(Bq, Bk, Bv, b3);
    gemmW<0><<<(NROW/128)*(3072/256), 512, 0, stream>>>(
        hb, wT3, b3, nullptr, nullptr, qkv, nullptr, NROW, 3072, HID);

    attn_k<<<256, 256, 0, stream>>>(qkv, attb);

    wcvt<<<(HID/32)*(HID/32), 256, 0, stream>>>(Wo, wT, HID, HID);
    gemmW<2><<<(NROW/128)*(HID/256), 512, 0, stream>>>(
        attb, wT, Bo, h, h, nullptr, part, NROW, HID, HID);
    reduce2<<<1, 256, 0, stream>>>(part, stats, (NROW/128)*(HID/256));
    ln_norm<<<2048, 256, 0, stream>>>(h, stats, h, hb, n4);

    wcvt<<<(HID/32)*(FFD/32), 256, 0, stream>>>(W1, wT, HID, FFD);
    gemmW<1><<<(NROW/128)*(FFD/256), 512, 0, stream>>>(
        hb, wT, B1, nullptr, nullptr, ff1, nullptr, NROW, FFD, HID);
    wcvt<<<(FFD/32)*(HID/32), 256, 0, stream>>>(W2, wT, FFD, HID);
    gemmW<2><<<(NROW/128)*(HID/256), 512, 0, stream>>>(
        ff1, wT, B2, h, h, nullptr, part, NROW, HID, FFD);
    reduce2<<<1, 256, 0, stream>>>(part, stats, (NROW/128)*(HID/256));
    ln_norm<<<2048, 256, 0, stream>>>(h, stats, (i == 5) ? (float*)d_out : h, hb, n4);
  }
}

// Round 7
// 3776.203 us; speedup vs baseline: 1.2611x; 1.1488x over previous
//
#include <hip/hip_runtime.h>
#include <hip/hip_bf16.h>
#include <stdint.h>

typedef __bf16 bf16_t;
typedef __bf16 bf16x8 __attribute__((ext_vector_type(8)));
typedef __bf16 bf16x4 __attribute__((ext_vector_type(4)));
typedef float  f32x16 __attribute__((ext_vector_type(16)));

#define SEQ   512
#define BATCH 32
#define HID   1024
#define FFD   4096
#define NROW  (SEQ*BATCH)          /* 16384 rows */
#define NTOT  ((long)NROW*HID)     /* 16,777,216 */
#define QKVS  3072

typedef __attribute__((address_space(3))) uint32_t lds_u32;
typedef __attribute__((address_space(1))) const uint32_t glb_u32;

__device__ __forceinline__ void gload_lds16(const void* g, void* l) {
  glb_u32* gp = reinterpret_cast<glb_u32*>(reinterpret_cast<uintptr_t>(g));
  lds_u32* lp = reinterpret_cast<lds_u32*>(reinterpret_cast<uintptr_t>(l));
  __builtin_amdgcn_global_load_lds(gp, lp, 16, 0, 0);
}

// ------------- embedding: hb = bf16(emb[x]*32 + pos[s]); init stId ---------
__global__ __launch_bounds__(256) void embed_k(const int* __restrict__ x,
    const float* __restrict__ emb, const float* __restrict__ pos,
    bf16_t* __restrict__ hb, float* __restrict__ stId)
{
  if (blockIdx.x == 0 && threadIdx.x == 0) { stId[0] = 0.f; stId[1] = 1.f; }
  const long row = blockIdx.x;           // row = s*32 + b
  const int  s   = (int)(row >> 5);
  const long idx = x[row];
  const int  t   = threadIdx.x;
  float4 e  = ((const float4*)(emb + idx*HID))[t];
  float4 pv = ((const float4*)(pos + (long)s*HID))[t];
  bf16x4 ob = {(bf16_t)(e.x*32.f+pv.x), (bf16_t)(e.y*32.f+pv.y),
               (bf16_t)(e.z*32.f+pv.z), (bf16_t)(e.w*32.f+pv.w)};
  *(bf16x4*)(hb + row*HID + (long)t*4) = ob;
}

// ---- weight convert+transpose 64x64 tile: wT[n][k] = bf16(w[k][n]) --------
__device__ __forceinline__ void wcvt64_body(const float* __restrict__ W,
    bf16_t* __restrict__ wT, int K, int N, int bid)
{
  __shared__ float t64[64][68];
  const int t = threadIdx.x;
  const int ntx = N >> 6;
  const int n0 = (bid % ntx) << 6, k0 = (bid / ntx) << 6;
  const int r0 = t >> 4, c4 = (t & 15) << 2;
#pragma unroll
  for (int i = 0; i < 4; ++i)
    *(float4*)&t64[r0 + i*16][c4] = *(const float4*)&W[(long)(k0 + r0 + i*16)*N + n0 + c4];
  __syncthreads();
  const int n = t >> 2, kg = (t & 3) << 4;
#pragma unroll
  for (int i = 0; i < 4; ++i) {
    const int k = kg + i*4;
    bf16x4 o = {(bf16_t)t64[k][n], (bf16_t)t64[k+1][n],
                (bf16_t)t64[k+2][n], (bf16_t)t64[k+3][n]};
    *(bf16x4*)&wT[(long)(n0 + n)*K + k0 + k] = o;
  }
}

// ---- column sums: out[n] = sum_k W[k][n] ----------------------------------
__device__ __forceinline__ void csum_body(const float* __restrict__ W,
    float* __restrict__ out, int K, int N, int bid)
{
  const int n = bid*256 + threadIdx.x;
  float s = 0.f;
  for (int k = 0; k < K; ++k) s += W[(long)k*N + n];
  out[n] = s;
}

// prologue: convert layer-0 QKV weights (768 blocks of 64x64 tiles)
__global__ __launch_bounds__(256) void prep0(const float* __restrict__ wq,
    const float* __restrict__ wk, const float* __restrict__ wv,
    bf16_t* __restrict__ wT3)
{
  const int sel = blockIdx.x >> 8, bid = blockIdx.x & 255;
  const float* W = sel == 0 ? wq : sel == 1 ? wk : wv;
  wcvt64_body(W, wT3 + (size_t)sel*HID*HID, HID, HID, bid);
}

// ====== bf16 MFMA GEMM, 128x256 tile, BK=64, 8 waves, 32x32x16, LN-fold ====
// C = A[M,K] * Bt[N,K]^T with epilogues:
// MODE 3: out = bf16( rstd*acc + (bias - mean*rstd*cs[col]) )          (QKV)
// MODE 4: out = bf16( relu(same) )                                     (FFN1)
// MODE 5: out = bf16( acc + bias + (res-mean)*rstd ); LN partials      (wo/FFN2)
// bias: 3-way select when N==3072 (fused QKV), else ba[col].
template<int MODE>
__global__ __launch_bounds__(512, 4)
void gemmW(const bf16_t* __restrict__ A, const bf16_t* __restrict__ Bt,
           const float* __restrict__ ba, const float* __restrict__ bb,
           const float* __restrict__ bc, const float* __restrict__ cs,
           const float* __restrict__ stats, const bf16_t* __restrict__ res,
           bf16_t* __restrict__ outB, float* __restrict__ part,
           int M, int N, int K)
{
  __shared__ bf16_t As[128][64];
  __shared__ bf16_t Bs[256][64];
  __shared__ float  rs[512], rq[512];
  const int tid = threadIdx.x;
  const int w = tid >> 6, l = tid & 63;
  const int wm = w >> 2, wn = w & 3;
  const int lr = l & 31, hi = l >> 5;

  const int nbn = N >> 8;
  const int nwg = gridDim.x;
  const int q8 = nwg >> 3, r8 = nwg & 7;
  const int xcd = blockIdx.x & 7, bidx = blockIdx.x >> 3;
  const int wg = (xcd < r8 ? xcd*(q8+1) : r8*(q8+1) + (xcd-r8)*q8) + bidx;
  const long bm = wg / nbn, bn = wg % nbn;
  const long rA0 = bm << 7, rB0 = bn << 8;

  const int srow   = tid >> 3;
  const int schunk = (((tid & 7) ^ ((tid >> 3) & 7)) << 3);
  const int ldsw   = (tid >> 6) << 10;

  f32x16 a00 = {0}, a01 = {0}, a10 = {0}, a11 = {0};

#define STG_TILE(kt) do { \
    const long kb_ = (long)(kt)*64 + schunk; \
    gload_lds16(A  + (rA0 + srow)*(long)K + kb_,        (char*)As + ldsw); \
    gload_lds16(A  + (rA0 + 64 + srow)*(long)K + kb_,   (char*)As + 8192 + ldsw); \
    gload_lds16(Bt + (rB0 + srow)*(long)K + kb_,        (char*)Bs + ldsw); \
    gload_lds16(Bt + (rB0 + 64 + srow)*(long)K + kb_,   (char*)Bs + 8192 + ldsw); \
    gload_lds16(Bt + (rB0 + 128 + srow)*(long)K + kb_,  (char*)Bs + 16384 + ldsw); \
    gload_lds16(Bt + (rB0 + 192 + srow)*(long)K + kb_,  (char*)Bs + 24576 + ldsw); \
  } while (0)
#define FRA(mt, kk) (*(const bf16x8*)((const char*)As + (wm*64 + (mt)*32 + lr)*128 + \
                      ((((kk)*2 + hi) ^ (l & 7)) << 4)))
#define FRB(nt, kk) (*(const bf16x8*)((const char*)Bs + (wn*64 + (nt)*32 + lr)*128 + \
                      ((((kk)*2 + hi) ^ (l & 7)) << 4)))

  const int nk = K >> 6;
  for (int t = 0; t < nk; ++t) {
    __syncthreads();
    STG_TILE(t);
    __syncthreads();
#pragma unroll
    for (int kk = 0; kk < 4; ++kk) {
      bf16x8 fa0 = FRA(0, kk), fa1 = FRA(1, kk);
      bf16x8 fb0 = FRB(0, kk), fb1 = FRB(1, kk);
      a00 = __builtin_amdgcn_mfma_f32_32x32x16_bf16(fa0, fb0, a00, 0, 0, 0);
      a01 = __builtin_amdgcn_mfma_f32_32x32x16_bf16(fa0, fb1, a01, 0, 0, 0);
      a10 = __builtin_amdgcn_mfma_f32_32x32x16_bf16(fa1, fb0, a10, 0, 0, 0);
      a11 = __builtin_amdgcn_mfma_f32_32x32x16_bf16(fa1, fb1, a11, 0, 0, 0);
    }
  }
#undef STG_TILE
#undef FRA
#undef FRB

  const float mS = stats[0], rS = stats[1];
  const bool q3 = (N == 3072);
  float ls = 0.f, lsq = 0.f;
  const long rowT = rA0 + wm*64 + 4*hi;
  const long colT = rB0 + wn*64 + lr;
#pragma unroll
  for (int nt = 0; nt < 2; ++nt) {
    const long col = colT + nt*32;
    float bv;
    if (MODE == 3 && q3)
      bv = col < 1024 ? ba[col] : col < 2048 ? bb[col - 1024] : bc[col - 2048];
    else
      bv = ba[col];
    float beta = 0.f;
    if (MODE == 3 || MODE == 4) beta = bv - mS*rS*cs[col];
#pragma unroll
    for (int mt = 0; mt < 2; ++mt) {
      const f32x16 acc = mt == 0 ? (nt == 0 ? a00 : a01) : (nt == 0 ? a10 : a11);
#pragma unroll
      for (int r = 0; r < 16; ++r) {
        const long row = rowT + mt*32 + (r & 3) + 8*(r >> 2);
        const long off = row*(long)N + col;
        float v;
        if (MODE == 3)      v = fmaf(acc[r], rS, beta);
        else if (MODE == 4) v = fmaxf(fmaf(acc[r], rS, beta), 0.f);
        else {
          v = acc[r] + bv + ((float)res[off] - mS)*rS;
          ls += v; lsq += v*v;
        }
        outB[off] = (bf16_t)v;
      }
    }
  }
  if (MODE == 5) {
    rs[tid] = ls; rq[tid] = lsq;
    __syncthreads();
    for (int o = 256; o > 0; o >>= 1) {
      if (tid < o) { rs[tid] += rs[tid+o]; rq[tid] += rq[tid+o]; }
      __syncthreads();
    }
    if (tid == 0) { part[2*blockIdx.x] = rs[0]; part[2*blockIdx.x + 1] = rq[0]; }
  }
}

// ====== fused: attention (blocks 0..255) + weight prep ride-along ==========
__global__ __launch_bounds__(256) void attn_fused(
    const bf16_t* __restrict__ qkv, bf16_t* __restrict__ ob,
    const float* __restrict__ Wo, bf16_t* __restrict__ wTo,
    const float* __restrict__ W1, bf16_t* __restrict__ wT1, float* __restrict__ cs1,
    const float* __restrict__ W2, bf16_t* __restrict__ wT2,
    const float* __restrict__ Wqn, const float* __restrict__ Wkn,
    const float* __restrict__ Wvn, bf16_t* __restrict__ wT3,
    float* __restrict__ cs3, int haveNext)
{
  const int blk = blockIdx.x;
  if (blk >= 256) {
    const int b = blk - 256;
    if (b < 256)        wcvt64_body(Wo, wTo, HID, HID, b);
    else if (b < 1280)  wcvt64_body(W1, wT1, HID, FFD, b - 256);
    else if (b < 2304)  wcvt64_body(W2, wT2, FFD, HID, b - 1280);
    else if (b < 2320)  csum_body(W1, cs1, HID, FFD, b - 2304);
    else if (haveNext) {
      if (b < 3088) {
        const int i = b - 2320, sel = i >> 8;
        const float* W = sel == 0 ? Wqn : sel == 1 ? Wkn : Wvn;
        wcvt64_body(W, wT3 + (size_t)sel*HID*HID, HID, HID, i & 255);
      } else {
        const int i = b - 3088, sel = i >> 2;
        const float* W = sel == 0 ? Wqn : sel == 1 ? Wkn : Wvn;
        csum_body(W, cs3 + sel*1024, HID, HID, i & 3);
      }
    }
    return;
  }

  // ---------------- attention proper (unchanged structure) ----------------
  __shared__ __align__(16) char smem[64*128*2*2 + 64*64*4 + 64*4];
  bf16_t* Qc = (bf16_t*)smem;
  bf16_t* Kc = (bf16_t*)(smem + 16384);
  bf16_t* Vc = (bf16_t*)smem;                  // aliases Qc (phase-disjoint)
  float*  E    = (float*)(smem + 32768);
  float*  Rinv = (float*)(smem + 49152);

  const int tid  = threadIdx.x;
  const int head = blk & 7, b = blk >> 3;
  const long rbase = (long)head*32 + b;

  const int ti = tid >> 2, g = tid & 3;
  const int lr  = tid >> 2;
  const int lp0 = (tid & 3) * 4;

  float eacc[16];
#pragma unroll
  for (int j = 0; j < 16; ++j) eacc[j] = 0.f;

  for (int kc = 0; kc < HID; kc += 128) {
    __syncthreads();
    const bf16_t* qrow = qkv + (lr*256 + rbase)*QKVS + kc;
    const bf16_t* krow = qkv + (lr*256 + rbase)*QKVS + 1024 + kc;
#pragma unroll
    for (int i = 0; i < 4; ++i) {
      const int p = lp0 + i;
      const int src = (p ^ (lr & 7)) * 8;
      *(uint4*)&Qc[lr*128 + p*8] = *(const uint4*)&qrow[src];
      *(uint4*)&Kc[lr*128 + p*8] = *(const uint4*)&krow[src];
    }
    __syncthreads();
    for (int e8 = 0; e8 < 16; ++e8) {
      const int qp = e8 ^ (ti & 7);
      bf16x8 qv = *(bf16x8*)&Qc[ti*128 + qp*8];
      float qf[8];
#pragma unroll
      for (int u = 0; u < 8; ++u) qf[u] = (float)qv[u];
#pragma unroll
      for (int j = 0; j < 16; ++j) {
        const int s  = j*4 + g;
        const int kp = e8 ^ (s & 7);
        bf16x8 kv = *(bf16x8*)&Kc[s*128 + kp*8];
        float a = eacc[j];
#pragma unroll
        for (int u = 0; u < 8; ++u) a += qf[u] * (float)kv[u];
        eacc[j] = a;
      }
    }
  }
  const float scale = 0.0883883476483184f;     // 1/sqrt(128)
  float mx = -1e30f;
#pragma unroll
  for (int j = 0; j < 16; ++j) { eacc[j] *= scale; mx = fmaxf(mx, eacc[j]); }
  mx = fmaxf(mx, __shfl_xor(mx, 1));
  mx = fmaxf(mx, __shfl_xor(mx, 2));
  float sum = 0.f;
#pragma unroll
  for (int j = 0; j < 16; ++j) {
    const float pj = __expf(eacc[j] - mx);
    E[(j*4 + g)*64 + ti] = pj;
    sum += pj;
  }
  sum += __shfl_xor(sum, 1);
  sum += __shfl_xor(sum, 2);
  if (g == 0) Rinv[ti] = 1.f / sum;
  __syncthreads();

  const int lane = tid & 63, wq_ = tid >> 6;
  const float rv = Rinv[lane];
  const long orow = (long)lane*256 + b*8 + head;
  for (int fc = 0; fc < HID; fc += 128) {
    __syncthreads();
    const bf16_t* vrow = qkv + (lr*256 + rbase)*QKVS + 2048 + fc;
#pragma unroll
    for (int i = 0; i < 4; ++i) {
      const int p = lp0 + i;
      *(uint4*)&Vc[lr*128 + p*8] = *(const uint4*)&vrow[p*8];
    }
    __syncthreads();
    float vacc[32];
#pragma unroll
    for (int u = 0; u < 32; ++u) vacc[u] = 0.f;
    for (int s = 0; s < 64; ++s) {
      const float pp = E[s*64 + lane];
#pragma unroll
      for (int u = 0; u < 4; ++u) {
        bf16x8 vv = *(bf16x8*)&Vc[s*128 + wq_*32 + u*8];
#pragma unroll
        for (int t8 = 0; t8 < 8; ++t8) vacc[u*8 + t8] += pp * (float)vv[t8];
      }
    }
#pragma unroll
    for (int u = 0; u < 4; ++u) {
      bf16x8 ov;
#pragma unroll
      for (int t8 = 0; t8 < 8; ++t8) ov[t8] = (bf16_t)(vacc[u*8 + t8] * rv);
      *(bf16x8*)&ob[orow*HID + fc + wq_*32 + u*8] = ov;
    }
  }
}

// -------- LN stage 2: sum per-block partials (np pairs) -> mean/rstd -------
__global__ __launch_bounds__(256) void reduce2(const float* __restrict__ part,
                                               float* __restrict__ stats, int np)
{
  __shared__ double sh[256], sh2[256];
  const int tid = threadIdx.x;
  double s = 0.0, s2 = 0.0;
  for (int i = tid; i < np; i += 256) { s += part[2*i]; s2 += part[2*i + 1]; }
  sh[tid] = s; sh2[tid] = s2; __syncthreads();
  for (int o = 128; o > 0; o >>= 1) {
    if (tid < o) { sh[tid] += sh[tid+o]; sh2[tid] += sh2[tid+o]; }
    __syncthreads();
  }
  if (tid == 0) {
    const double n = (double)NTOT;
    const double mean = sh[0] / n;
    const double var  = sh2[0] / n - mean*mean;
    stats[0] = (float)mean;
    stats[1] = (float)(1.0 / sqrt(var + 1e-5));
  }
}

// -------- final: d_out(f32) = (t2_raw - mean)*rstd -------------------------
__global__ __launch_bounds__(256) void final_norm(const bf16_t* __restrict__ t,
    const float* __restrict__ stats, float* __restrict__ out)
{
  const float m = stats[0], r = stats[1];
  const long n8 = NTOT / 8;
  for (long i = (long)blockIdx.x*blockDim.x + threadIdx.x; i < n8;
       i += (long)gridDim.x*blockDim.x) {
    bf16x8 v = ((const bf16x8*)t)[i];
    float4 o0 = {((float)v[0]-m)*r, ((float)v[1]-m)*r, ((float)v[2]-m)*r, ((float)v[3]-m)*r};
    float4 o1 = {((float)v[4]-m)*r, ((float)v[5]-m)*r, ((float)v[6]-m)*r, ((float)v[7]-m)*r};
    ((float4*)out)[2*i]   = o0;
    ((float4*)out)[2*i+1] = o1;
  }
}

// ---------------------------------------------------------------------------
extern "C" void kernel_launch(void* const* d_in, const int* in_sizes, int n_in,
                              void* d_out, int out_size, void* d_ws, size_t ws_size,
                              hipStream_t stream)
{
  const int*   x    = (const int*)  d_in[0];
  const float* emb  = (const float*)d_in[1];
  const float* pos  = (const float*)d_in[2];
  const float* wq_a = (const float*)d_in[3];
  const float* bq_a = (const float*)d_in[4];
  const float* wk_a = (const float*)d_in[5];
  const float* bk_a = (const float*)d_in[6];
  const float* wv_a = (const float*)d_in[7];
  const float* bv_a = (const float*)d_in[8];
  const float* wo_a = (const float*)d_in[9];
  const float* bo_a = (const float*)d_in[10];
  const float* w1_a = (const float*)d_in[11];
  const float* b1_a = (const float*)d_in[12];
  const float* w2_a = (const float*)d_in[13];
  const float* b2_a = (const float*)d_in[14];

  char* p = (char*)d_ws;
  auto take = [&](size_t n) { char* r = p; p += (n + 255) & ~(size_t)255; return r; };
  bf16_t* hb   = (bf16_t*)take(NTOT*2);                 // raw hidden (rolling)
  bf16_t* U    = (bf16_t*)take((size_t)NROW*FFD*2);     // 128 MB union
  bf16_t* qkv  = U;                                     // NROW x 3072
  bf16_t* attb = U + 3*NTOT;
  bf16_t* ffb  = U;                                     // overlays qkv (dead)
  bf16_t* wTo  = (bf16_t*)take((size_t)HID*HID*2);
  bf16_t* wT1  = (bf16_t*)take((size_t)HID*FFD*2);
  bf16_t* wT2  = (bf16_t*)take((size_t)HID*FFD*2);
  bf16_t* wT3  = (bf16_t*)take((size_t)3*HID*HID*2);
  float*  cs1  = (float*) take(FFD*4);
  float*  cs3  = (float*) take(QKVS*4);
  float*  part = (float*) take(4096*4);
  float*  stId = (float*) take(256);
  float*  st1  = (float*) take(256);
  float*  st2  = (float*) take(256);

  const int gQKV = (NROW/128)*(QKVS/256);   // 1536
  const int gH   = (NROW/128)*(HID/256);    // 512
  const int gF   = (NROW/128)*(FFD/256);    // 2048

  embed_k<<<NROW, 256, 0, stream>>>(x, emb, pos, hb, stId);
  prep0<<<768, 256, 0, stream>>>(wq_a, wk_a, wv_a, wT3);

  for (int i = 0; i < 6; ++i) {
    const float* Bq = bq_a + (size_t)i*HID;
    const float* Bk = bk_a + (size_t)i*HID;
    const float* Bv = bv_a + (size_t)i*HID;
    const float* Wo = wo_a + (size_t)i*HID*HID;  const float* Bo = bo_a + (size_t)i*HID;
    const float* W1 = w1_a + (size_t)i*HID*FFD;  const float* B1 = b1_a + (size_t)i*FFD;
    const float* W2 = w2_a + (size_t)i*FFD*HID;  const float* B2 = b2_a + (size_t)i*HID;
    const float* stIn = (i == 0) ? stId : st2;
    const int haveNext = (i < 5);
    const float* Wqn = wq_a + (size_t)(i+1)*HID*HID;
    const float* Wkn = wk_a + (size_t)(i+1)*HID*HID;
    const float* Wvn = wv_a + (size_t)(i+1)*HID*HID;

    // QKV projection with LN fold (identity for layer 0)
    gemmW<3><<<gQKV, 512, 0, stream>>>(hb, wT3, Bq, Bk, Bv, cs3, stIn,
                                       nullptr, qkv, nullptr, NROW, QKVS, HID);

    // attention + ride-along weight prep (Wo/W1/W2/cs1 + next QKV/cs3)
    attn_fused<<<haveNext ? 3100 + 256 : 2576, 256, 0, stream>>>(
        qkv, attb, Wo, wTo, W1, wT1, cs1, W2, wT2,
        Wqn, Wkn, Wvn, wT3, cs3, haveNext);

    // wo projection + residual fold + LN partials -> t1 (in-place hb)
    gemmW<5><<<gH, 512, 0, stream>>>(attb, wTo, Bo, Bo, Bo, nullptr, stIn,
                                     hb, hb, part, NROW, HID, HID);
    reduce2<<<1, 256, 0, stream>>>(part, st1, gH);

    // FFN1 with LN fold + relu
    gemmW<4><<<gF, 512, 0, stream>>>(hb, wT1, B1, B1, B1, cs1, st1,
                                     nullptr, ffb, nullptr, NROW, FFD, HID);

    // FFN2 + residual fold + LN partials -> t2 (in-place hb)
    gemmW<5><<<gH, 512, 0, stream>>>(ffb, wT2, B2, B2, B2, nullptr, st1,
                                     hb, hb, part, NROW, HID, FFD);
    reduce2<<<1, 256, 0, stream>>>(part, st2, gH);
  }

  final_norm<<<2048, 256, 0, stream>>>(hb, st2, (float*)d_out);
}